// Round 5
// baseline (413.011 us; speedup 1.0000x reference)
//
#include <hip/hip_runtime.h>

// MQA: B=2, S=2048, D=2048, H=16, HD=128.  GEMMs bf16 MFMA 16x16x32, fp32 acc.
// v9: attention = v8 (8 waves x 32 q-rows, K+V double-buffered, 1 barrier/kt)
// with HALF-TILE software pipelining inside each iteration:
//   QK-half1 MFMAs issued BEFORE softmax-half0 (disjoint regs s[][4..7] vs
//   s[][0..3]) and PV-half0 MFMAs issued BEFORE softmax-half1 -> each MFMA
//   cluster executes while the SAME wave's VALU does the other half's softmax.
// + defer-max (T13, exponent slack 8 => p<=256, bf16-safe): skip max-update/
//   alpha/O-rescale unless any lane's tile-max grows >8 exponent units (rare
//   after tile 0; the old exact skip ~never fired across 32 rows).
// + first MFMA of each accumulator uses C=zero reg (no 64 zero-init movs).
// GEMM core unchanged; Q-proj + KV-proj fused; 4 transposes fused.

typedef unsigned short u16;
typedef __attribute__((ext_vector_type(8))) short bf16x8;   // 8 bf16 = 4 VGPR
typedef __attribute__((ext_vector_type(4))) short bf16x4;   // 4 bf16 = 2 VGPR
typedef __attribute__((ext_vector_type(4))) float f32x4;

#define D_MODEL 2048
#define SEQ     2048
#define NH      16
#define HD      128
#define BK      32

__device__ __forceinline__ u16 f2bf(float f){
  union { float f; unsigned u; } v; v.f = f;
  unsigned r = (v.u + 0x7FFFu + ((v.u >> 16) & 1u)) >> 16;  // RNE
  return (u16)r;
}

#if __has_builtin(__builtin_amdgcn_cvt_pk_bf16_f32)
__device__ __forceinline__ unsigned pack2bf(float a, float b){
  auto v = __builtin_amdgcn_cvt_pk_bf16_f32(a, b);
  unsigned u; __builtin_memcpy(&u, &v, 4); return u;
}
#else
__device__ __forceinline__ unsigned pack2bf(float a, float b){
  return (unsigned)f2bf(a) | ((unsigned)f2bf(b) << 16);
}
#endif

__device__ __forceinline__ void gll16(const void* g, void* l){
  __builtin_amdgcn_global_load_lds(
      (const __attribute__((address_space(1))) void*)g,
      (__attribute__((address_space(3))) void*)l, 16, 0, 0);
}

// ---------------- fp32 -> bf16 conversion of q,k,v ----------------
__global__ __launch_bounds__(256) void convert3_kernel(
    const float4* __restrict__ a, const float4* __restrict__ b, const float4* __restrict__ c,
    ushort4* __restrict__ oa, ushort4* __restrict__ ob, ushort4* __restrict__ oc){
  int i = blockIdx.x*256 + threadIdx.x;
  float4 va = a[i], vb = b[i], vc = c[i];
  ushort4 ra, rb, rc;
  ra.x=f2bf(va.x); ra.y=f2bf(va.y); ra.z=f2bf(va.z); ra.w=f2bf(va.w);
  rb.x=f2bf(vb.x); rb.y=f2bf(vb.y); rb.z=f2bf(vb.z); rb.w=f2bf(vb.w);
  rc.x=f2bf(vc.x); rc.y=f2bf(vc.y); rc.z=f2bf(vc.z); rc.w=f2bf(vc.w);
  oa[i]=ra; ob[i]=rb; oc[i]=rc;
}

// ---------------- all 4 weight transposes in one launch ----------------
__global__ __launch_bounds__(256) void transpose_all(
    const float* __restrict__ Wq, const float* __restrict__ Wo,
    const float* __restrict__ Wk, const float* __restrict__ Wv,
    u16* __restrict__ WqT, u16* __restrict__ WoT,
    u16* __restrict__ WkT, u16* __restrict__ WvT){
  __shared__ float tt[32][33];
  int id = blockIdx.x;
  const float* in; u16* outp; int C, bx, by;
  if (id < 4096)      { in=Wq; outp=WqT; C=2048; bx=id&63;        by=id>>6; }
  else if (id < 8192) { id-=4096; in=Wo; outp=WoT; C=2048; bx=id&63; by=id>>6; }
  else if (id < 8448) { id-=8192; in=Wk; outp=WkT; C=128;  bx=id&3;  by=id>>2; }
  else                { id-=8448; in=Wv; outp=WvT; C=128;  bx=id&3;  by=id>>2; }
  const int R = 2048;
  int c0 = bx*32, r0 = by*32;
  int tx = threadIdx.x & 31, ty = threadIdx.x >> 5;   // (32,8) flattened
  #pragma unroll
  for (int k=0;k<4;k++) tt[ty+k*8][tx] = in[(size_t)(r0+ty+k*8)*C + c0+tx];
  __syncthreads();
  #pragma unroll
  for (int k=0;k<4;k++) outp[(size_t)(c0+ty+k*8)*R + r0+tx] = f2bf(tt[tx][ty+k*8]);
}

// ---------------- double-buffered GEMM core: 1 barrier/iter ----------------
__device__ __forceinline__ void gemm_core_db(
    const u16* __restrict__ A, const u16* __restrict__ BT,
    int lda, int ldb, int m0, int n0, int kbeg, int kend,
    u16* As, u16* Bs, f32x4 acc[4][4])
{
  const int t = threadIdx.x;
  const int w = t >> 6, l = t & 63;
  const int wr = w >> 1, wc = w & 1;
  const int c16 = l & 15, q = l >> 4;
  const int srow = l >> 2;
  const int sc   = ((l & 3) ^ ((l >> 3) & 3)) * 8;

  int aoff[4], boff[4];
  #pragma unroll
  for (int mt=0;mt<4;mt++){
    int row = wr*64 + mt*16 + c16;
    aoff[mt] = row*BK + ((q ^ ((row>>1)&3))*8);
  }
  #pragma unroll
  for (int nt=0;nt<4;nt++){
    int row = wc*64 + nt*16 + c16;
    boff[nt] = row*BK + ((q ^ ((row>>1)&3))*8);
  }

  auto issue = [&](int k0, int buf){
    u16* Ad = As + buf*4096;
    u16* Bd = Bs + buf*4096;
    #pragma unroll
    for (int half=0; half<2; half++){
      int r = half*64 + w*16 + srow;
      gll16(A  + (size_t)(m0+r)*lda + k0 + sc, Ad + (half*64 + w*16)*BK);
      gll16(BT + (size_t)(n0+r)*ldb + k0 + sc, Bd + (half*64 + w*16)*BK);
    }
  };

  const int n = (kend - kbeg) / BK;
  issue(kbeg, 0);
  for (int i = 0; i < n; i++){
    __syncthreads();                       // tile i arrived; buf (i+1)&1 free
    if (i+1 < n) issue(kbeg + (i+1)*BK, (i+1)&1);
    const u16* Ab = As + (i&1)*4096;
    const u16* Bb = Bs + (i&1)*4096;
    bf16x8 af[4], bfr[4];
    #pragma unroll
    for (int mt=0;mt<4;mt++) af[mt]  = *(const bf16x8*)(Ab + aoff[mt]);
    #pragma unroll
    for (int nt=0;nt<4;nt++) bfr[nt] = *(const bf16x8*)(Bb + boff[nt]);
    #pragma unroll
    for (int mt=0;mt<4;mt++)
      #pragma unroll
      for (int nt=0;nt<4;nt++)
        acc[mt][nt] = __builtin_amdgcn_mfma_f32_16x16x32_bf16(af[mt], bfr[nt], acc[mt][nt], 0,0,0);
  }
}

// ---------------- fused Q-projection + K/V projection ----------------
__global__ __launch_bounds__(256) void proj_kernel(
    const u16* __restrict__ qb, const u16* __restrict__ kb, const u16* __restrict__ vb,
    const u16* __restrict__ WqT, const u16* __restrict__ WkT, const u16* __restrict__ WvT,
    const float* __restrict__ bq, u16* __restrict__ Qp, float* __restrict__ part)
{
  __shared__ u16 As[2*4096], Bs[2*4096];
  f32x4 acc[4][4];
  f32x4 z = {0.f,0.f,0.f,0.f};
  #pragma unroll
  for (int i=0;i<4;i++) for (int j=0;j<4;j++) acc[i][j] = z;
  const int t = threadIdx.x, w = t>>6, l = t&63, wr = w>>1, wc = w&1, c16 = l&15, q = l>>4;
  int id = blockIdx.x;
  if (id < 512){
    int m0 = (id & 31)*128, n0 = (id >> 5)*128;
    gemm_core_db(qb, WqT, 2048, 2048, m0, n0, 0, 2048, As, Bs, acc);
    #pragma unroll
    for (int mt=0;mt<4;mt++)
      #pragma unroll
      for (int nt=0;nt<4;nt++){
        int col = n0 + wc*64 + nt*16 + c16;
        float bv = bq[col];
        #pragma unroll
        for (int r=0;r<4;r++){
          int row = m0 + wr*64 + mt*16 + q*4 + r;
          Qp[(size_t)row*D_MODEL + col] = f2bf(acc[mt][nt][r] + bv);
        }
      }
  } else {
    int kvid = id - 512;
    int zi = kvid & 3, nb = (kvid >> 2) & 1, mi = kvid >> 3;
    const u16* Am = nb ? vb  : kb;
    const u16* Bm = nb ? WvT : WkT;
    gemm_core_db(Am, Bm, 2048, 2048, mi*128, 0, zi*512, zi*512+512, As, Bs, acc);
    float* dst = part + (size_t)(zi*2 + nb)*524288;   // [z][nb][4096][128]
    #pragma unroll
    for (int mt=0;mt<4;mt++)
      #pragma unroll
      for (int nt=0;nt<4;nt++){
        int col = wc*64 + nt*16 + c16;
        #pragma unroll
        for (int r=0;r<4;r++){
          int row = mi*128 + wr*64 + mt*16 + q*4 + r;
          dst[(size_t)row*128 + col] = acc[mt][nt][r];
        }
      }
  }
}

// ---------------- O-projection GEMM + bias, fp32 out ----------------
__global__ __launch_bounds__(256) void oproj_kernel(
    const u16* __restrict__ A, const u16* __restrict__ BT, const float* __restrict__ bias,
    float* __restrict__ C)
{
  __shared__ u16 As[2*4096], Bs[2*4096];
  f32x4 acc[4][4];
  f32x4 z = {0.f,0.f,0.f,0.f};
  #pragma unroll
  for (int i=0;i<4;i++) for (int j=0;j<4;j++) acc[i][j] = z;
  int m0 = blockIdx.x*128, n0 = blockIdx.y*128;
  gemm_core_db(A, BT, 2048, 2048, m0, n0, 0, 2048, As, Bs, acc);
  const int t = threadIdx.x, w = t>>6, l = t&63, wr = w>>1, wc = w&1, c16 = l&15, q = l>>4;
  #pragma unroll
  for (int mt=0;mt<4;mt++)
    #pragma unroll
    for (int nt=0;nt<4;nt++){
      int col = n0 + wc*64 + nt*16 + c16;
      float bv = bias[col];
      #pragma unroll
      for (int r=0;r<4;r++){
        int row = m0 + wr*64 + mt*16 + q*4 + r;
        C[(size_t)row*D_MODEL + col] = acc[mt][nt][r] + bv;
      }
    }
}

// ---------------- reduce split-K partials; Kp bf16 [4096][128], VpT bf16 [B][128][S] ----------------
__global__ __launch_bounds__(256) void kv_reduce_kernel(
    const float* __restrict__ part, const float* __restrict__ bk, const float* __restrict__ bv,
    u16* __restrict__ Kp, u16* __restrict__ VpT){
  int idx = blockIdx.x*256 + threadIdx.x;
  int d = idx & 127, sg = idx >> 7;
  float ka = 0.f, va = 0.f;
  #pragma unroll
  for (int zi=0; zi<4; zi++){
    ka += part[(size_t)(zi*2+0)*524288 + idx];
    va += part[(size_t)(zi*2+1)*524288 + idx];
  }
  Kp[idx] = f2bf(ka + bk[d]);
  int b = sg >> 11, sl = sg & 2047;
  VpT[(size_t)b*262144 + (size_t)d*2048 + sl] = f2bf(va + bv[d]);
}

// ---------------- flash attention v9 ----------------
// 8 waves x 32 q-rows (2 q-sets); grid (8,32) = 256 blocks = 1/CU.
// K+V double-buffered (128 KB LDS), 1 barrier/kt. Half-tile pipelined body:
//   glls(t+1) | QK-h0 | QK-h1 | SM-h0 | pack-h0 | PV-h0 | SM-h1 | pack-h1 |
//   PV-h1 | barrier.  QK-h1 overlaps SM-h0; PV-h0 overlaps SM-h1 (disjoint
//   register sets -> matrix pipe busy while VALU does softmax).
// Defer-max: skip m/alpha/O-rescale unless (vmax-m)*cs > 8 (p<=2^8).
__global__ __launch_bounds__(512, 2) void attn_kernel(
    const u16* __restrict__ Qp, const u16* __restrict__ Kp,
    const u16* __restrict__ VpT, u16* __restrict__ attnb){
  __shared__ u16 lds[65536];    // 128 KB
  const int t = threadIdx.x;
  const int w = t >> 6, l = t & 63;
  const int c16 = l & 15, q = l >> 4;

  const int qt = blockIdx.x;           // 0..7
  const int bh = blockIdx.y;           // 0..31
  const int b = bh >> 4, h = bh & 15;

  const u16* Qbase = Qp  + ((size_t)(b*SEQ + qt*256 + w*32))*D_MODEL + h*HD;
  const u16* Kbase = Kp  + (size_t)(b*SEQ)*HD;
  const u16* Vbase = VpT + (size_t)b*HD*SEQ;

  const int sr = w*4 + (l >> 4);       // staging row within 32-row group
  // ---- prologue: issue K0+V0 glls; Q frags global->reg ----
  #pragma unroll
  for (int j=0;j<4;j++){
    int r = j*32 + sr;
    int g = (l & 15) ^ (r & 15);
    gll16(Kbase + (size_t)r*HD + g*8, lds + j*4096 + w*512);
  }
  #pragma unroll
  for (int j=0;j<4;j++){
    int d = j*32 + sr;
    int g = (l & 15) ^ (d & 15);
    gll16(Vbase + (size_t)d*SEQ + g*8, lds + 32768 + j*4096 + w*512);
  }
  bf16x8 qf[2][4];
  #pragma unroll
  for (int qs=0;qs<2;qs++)
    #pragma unroll
    for (int kk=0;kk<4;kk++)
      qf[qs][kk] = *(const bf16x8*)(Qbase + (size_t)(qs*16 + c16)*D_MODEL + (kk*4 + q)*8);
  __syncthreads();   // K0+V0 arrived

  f32x4 o[2][8];
  f32x4 z4 = {0.f,0.f,0.f,0.f};
  #pragma unroll
  for (int qs=0;qs<2;qs++) for (int dt=0;dt<8;dt++) o[qs][dt] = z4;
  float mrow[2] = {-1e30f, -1e30f};
  float lrow[2] = {0.f, 0.f};
  const float cs = 0.08838834764831845f * 1.4426950408889634f;  // (1/sqrt(128))*log2(e)

  for (int kt = 0; kt < 16; kt++){
    const int p = kt & 1;
    // issue ALL glls for tile kt+1 into the idle buffer (p^1)
    if (kt < 15){
      u16* Kd = lds + (p^1)*16384;
      u16* Vd = lds + 32768 + (p^1)*16384;
      #pragma unroll
      for (int j=0;j<4;j++){
        int r = j*32 + sr;
        int g = (l & 15) ^ (r & 15);
        gll16(Kbase + (size_t)((kt+1)*128 + r)*HD + g*8, Kd + j*4096 + w*512);
      }
      #pragma unroll
      for (int j=0;j<4;j++){
        int d = j*32 + sr;
        int g = (l & 15) ^ (d & 15);
        gll16(Vbase + (size_t)d*SEQ + (kt+1)*128 + g*8, Vd + j*4096 + w*512);
      }
    }
    const u16* Ks = lds + p*16384;
    const u16* Vs = lds + 32768 + p*16384;

    f32x4 s[2][8];
    union PU { unsigned u[4]; bf16x8 v; } P32[2][4];

    // ---- QK half0 (kt8 0..3): first kk uses C=z4 (no zero-init movs) ----
    __builtin_amdgcn_s_setprio(1);
    #pragma unroll
    for (int kt8=0; kt8<4; kt8++){
      {
        bf16x8 kf = *(const bf16x8*)(Ks + (kt8*16 + c16)*128 + ((q ^ c16) & 15)*8);
        s[0][kt8] = __builtin_amdgcn_mfma_f32_16x16x32_bf16(kf, qf[0][0], z4, 0,0,0);
        s[1][kt8] = __builtin_amdgcn_mfma_f32_16x16x32_bf16(kf, qf[1][0], z4, 0,0,0);
      }
      #pragma unroll
      for (int kk=1;kk<4;kk++){
        int ch = kk*4 + q;
        bf16x8 kf = *(const bf16x8*)(Ks + (kt8*16 + c16)*128 + ((ch ^ c16) & 15)*8);
        s[0][kt8] = __builtin_amdgcn_mfma_f32_16x16x32_bf16(kf, qf[0][kk], s[0][kt8], 0,0,0);
        s[1][kt8] = __builtin_amdgcn_mfma_f32_16x16x32_bf16(kf, qf[1][kk], s[1][kt8], 0,0,0);
      }
    }
    // ---- QK half1 (kt8 4..7): MFMAs issued BEFORE SM-h0 -> overlap ----
    #pragma unroll
    for (int kt8=4; kt8<8; kt8++){
      {
        bf16x8 kf = *(const bf16x8*)(Ks + (kt8*16 + c16)*128 + ((q ^ c16) & 15)*8);
        s[0][kt8] = __builtin_amdgcn_mfma_f32_16x16x32_bf16(kf, qf[0][0], z4, 0,0,0);
        s[1][kt8] = __builtin_amdgcn_mfma_f32_16x16x32_bf16(kf, qf[1][0], z4, 0,0,0);
      }
      #pragma unroll
      for (int kk=1;kk<4;kk++){
        int ch = kk*4 + q;
        bf16x8 kf = *(const bf16x8*)(Ks + (kt8*16 + c16)*128 + ((ch ^ c16) & 15)*8);
        s[0][kt8] = __builtin_amdgcn_mfma_f32_16x16x32_bf16(kf, qf[0][kk], s[0][kt8], 0,0,0);
        s[1][kt8] = __builtin_amdgcn_mfma_f32_16x16x32_bf16(kf, qf[1][kk], s[1][kt8], 0,0,0);
      }
    }
    __builtin_amdgcn_s_setprio(0);

    // ---- softmax half0 (reads s[*][0..3]; QK-h1 MFMAs run underneath) ----
    {
      float vmax[2];
      #pragma unroll
      for (int qs=0; qs<2; qs++){
        float x0 = fmaxf(fmaxf(s[qs][0][0],s[qs][0][1]), fmaxf(s[qs][0][2],s[qs][0][3]));
        float x1 = fmaxf(fmaxf(s[qs][1][0],s[qs][1][1]), fmaxf(s[qs][1][2],s[qs][1][3]));
        float x2 = fmaxf(fmaxf(s[qs][2][0],s[qs][2][1]), fmaxf(s[qs][2][2],s[qs][2][3]));
        float x3 = fmaxf(fmaxf(s[qs][3][0],s[qs][3][1]), fmaxf(s[qs][3][2],s[qs][3][3]));
        float vm = fmaxf(fmaxf(x0,x1), fmaxf(x2,x3));
        vm = fmaxf(vm, __shfl_xor(vm, 16));
        vm = fmaxf(vm, __shfl_xor(vm, 32));
        vmax[qs] = vm;
      }
      bool upd = ((vmax[0]-mrow[0])*cs > 8.f) || ((vmax[1]-mrow[1])*cs > 8.f);
      if (__any(upd)){                      // rare after tile 0
        #pragma unroll
        for (int qs=0; qs<2; qs++){
          float mnew = fmaxf(mrow[qs], vmax[qs]);
          float a = exp2f((mrow[qs]-mnew)*cs);
          mrow[qs] = mnew; lrow[qs] *= a;
          #pragma unroll
          for (int dt=0;dt<8;dt++)
            #pragma unroll
            for (int r=0;r<4;r++) o[qs][dt][r] *= a;
        }
      }
      #pragma unroll
      for (int qs=0; qs<2; qs++){
        float mc = mrow[qs]*cs;
        float rsum = 0.f;
        #pragma unroll
        for (int kt8=0;kt8<4;kt8++){
          float p0 = exp2f(__builtin_fmaf(s[qs][kt8][0], cs, -mc));
          float p1 = exp2f(__builtin_fmaf(s[qs][kt8][1], cs, -mc));
          float p2 = exp2f(__builtin_fmaf(s[qs][kt8][2], cs, -mc));
          float p3 = exp2f(__builtin_fmaf(s[qs][kt8][3], cs, -mc));
          s[qs][kt8][0]=p0; s[qs][kt8][1]=p1; s[qs][kt8][2]=p2; s[qs][kt8][3]=p3;
          rsum += (p0+p1)+(p2+p3);
        }
        rsum += __shfl_xor(rsum, 16);
        rsum += __shfl_xor(rsum, 32);
        lrow[qs] += rsum;
        P32[qs][0].u[0] = pack2bf(s[qs][0][0], s[qs][0][1]);
        P32[qs][0].u[1] = pack2bf(s[qs][0][2], s[qs][0][3]);
        P32[qs][0].u[2] = pack2bf(s[qs][1][0], s[qs][1][1]);
        P32[qs][0].u[3] = pack2bf(s[qs][1][2], s[qs][1][3]);
        P32[qs][1].u[0] = pack2bf(s[qs][2][0], s[qs][2][1]);
        P32[qs][1].u[1] = pack2bf(s[qs][2][2], s[qs][2][3]);
        P32[qs][1].u[2] = pack2bf(s[qs][3][0], s[qs][3][1]);
        P32[qs][1].u[3] = pack2bf(s[qs][3][2], s[qs][3][3]);
      }
    }

    // ---- PV half0 (kb 0,1; keys 0..63): issued BEFORE SM-h1 -> overlap ----
    __builtin_amdgcn_s_setprio(1);
    #pragma unroll
    for (int kb=0; kb<2; kb++){
      int ca = 4*kb + (q>>1);
      int cb = ca + 2;
      #pragma unroll
      for (int dt=0; dt<8; dt++){
        int d = dt*16 + c16;
        union VU { bf16x4 hh[2]; bf16x8 v; } vf;
        vf.hh[0] = *(const bf16x4*)(Vs + d*128 + ((ca ^ c16) & 15)*8 + (q&1)*4);
        vf.hh[1] = *(const bf16x4*)(Vs + d*128 + ((cb ^ c16) & 15)*8 + (q&1)*4);
        o[0][dt] = __builtin_amdgcn_mfma_f32_16x16x32_bf16(vf.v, P32[0][kb].v, o[0][dt], 0,0,0);
        o[1][dt] = __builtin_amdgcn_mfma_f32_16x16x32_bf16(vf.v, P32[1][kb].v, o[1][dt], 0,0,0);
      }
    }
    __builtin_amdgcn_s_setprio(0);

    // ---- softmax half1 (reads s[*][4..7]; PV-h0 MFMAs run underneath) ----
    {
      float vmax[2];
      #pragma unroll
      for (int qs=0; qs<2; qs++){
        float x0 = fmaxf(fmaxf(s[qs][4][0],s[qs][4][1]), fmaxf(s[qs][4][2],s[qs][4][3]));
        float x1 = fmaxf(fmaxf(s[qs][5][0],s[qs][5][1]), fmaxf(s[qs][5][2],s[qs][5][3]));
        float x2 = fmaxf(fmaxf(s[qs][6][0],s[qs][6][1]), fmaxf(s[qs][6][2],s[qs][6][3]));
        float x3 = fmaxf(fmaxf(s[qs][7][0],s[qs][7][1]), fmaxf(s[qs][7][2],s[qs][7][3]));
        float vm = fmaxf(fmaxf(x0,x1), fmaxf(x2,x3));
        vm = fmaxf(vm, __shfl_xor(vm, 16));
        vm = fmaxf(vm, __shfl_xor(vm, 32));
        vmax[qs] = vm;
      }
      bool upd = ((vmax[0]-mrow[0])*cs > 8.f) || ((vmax[1]-mrow[1])*cs > 8.f);
      if (__any(upd)){                      // very rare; o already holds PV-h0
        #pragma unroll
        for (int qs=0; qs<2; qs++){
          float mnew = fmaxf(mrow[qs], vmax[qs]);
          float a = exp2f((mrow[qs]-mnew)*cs);
          mrow[qs] = mnew; lrow[qs] *= a;
          #pragma unroll
          for (int dt=0;dt<8;dt++)
            #pragma unroll
            for (int r=0;r<4;r++) o[qs][dt][r] *= a;
        }
      }
      #pragma unroll
      for (int qs=0; qs<2; qs++){
        float mc = mrow[qs]*cs;
        float rsum = 0.f;
        #pragma unroll
        for (int kt8=4;kt8<8;kt8++){
          float p0 = exp2f(__builtin_fmaf(s[qs][kt8][0], cs, -mc));
          float p1 = exp2f(__builtin_fmaf(s[qs][kt8][1], cs, -mc));
          float p2 = exp2f(__builtin_fmaf(s[qs][kt8][2], cs, -mc));
          float p3 = exp2f(__builtin_fmaf(s[qs][kt8][3], cs, -mc));
          s[qs][kt8][0]=p0; s[qs][kt8][1]=p1; s[qs][kt8][2]=p2; s[qs][kt8][3]=p3;
          rsum += (p0+p1)+(p2+p3);
        }
        rsum += __shfl_xor(rsum, 16);
        rsum += __shfl_xor(rsum, 32);
        lrow[qs] += rsum;
        P32[qs][2].u[0] = pack2bf(s[qs][4][0], s[qs][4][1]);
        P32[qs][2].u[1] = pack2bf(s[qs][4][2], s[qs][4][3]);
        P32[qs][2].u[2] = pack2bf(s[qs][5][0], s[qs][5][1]);
        P32[qs][2].u[3] = pack2bf(s[qs][5][2], s[qs][5][3]);
        P32[qs][3].u[0] = pack2bf(s[qs][6][0], s[qs][6][1]);
        P32[qs][3].u[1] = pack2bf(s[qs][6][2], s[qs][6][3]);
        P32[qs][3].u[2] = pack2bf(s[qs][7][0], s[qs][7][1]);
        P32[qs][3].u[3] = pack2bf(s[qs][7][2], s[qs][7][3]);
      }
    }

    // ---- PV half1 (kb 2,3; keys 64..127) ----
    __builtin_amdgcn_s_setprio(1);
    #pragma unroll
    for (int kb=2; kb<4; kb++){
      int ca = 4*kb + (q>>1);
      int cb = ca + 2;
      #pragma unroll
      for (int dt=0; dt<8; dt++){
        int d = dt*16 + c16;
        union VU { bf16x4 hh[2]; bf16x8 v; } vf;
        vf.hh[0] = *(const bf16x4*)(Vs + d*128 + ((ca ^ c16) & 15)*8 + (q&1)*4);
        vf.hh[1] = *(const bf16x4*)(Vs + d*128 + ((cb ^ c16) & 15)*8 + (q&1)*4);
        o[0][dt] = __builtin_amdgcn_mfma_f32_16x16x32_bf16(vf.v, P32[0][kb].v, o[0][dt], 0,0,0);
        o[1][dt] = __builtin_amdgcn_mfma_f32_16x16x32_bf16(vf.v, P32[1][kb].v, o[1][dt], 0,0,0);
      }
    }
    __builtin_amdgcn_s_setprio(0);
    __syncthreads();   // drains tile kt+1 glls; certifies buf p readers done
  }

  // normalize + write: lane holds O[q=c16+16qs][d=dt*16+quad*4+r]
  #pragma unroll
  for (int qs=0;qs<2;qs++){
    float inv = 1.f / lrow[qs];
    int qrow = qt*256 + w*32 + qs*16 + c16;
    u16* dst = attnb + ((size_t)(b*SEQ) + qrow)*D_MODEL + h*HD + q*4;
    #pragma unroll
    for (int dt=0;dt<8;dt++){
      ushort4 pk;
      pk.x = f2bf(o[qs][dt][0]*inv);
      pk.y = f2bf(o[qs][dt][1]*inv);
      pk.z = f2bf(o[qs][dt][2]*inv);
      pk.w = f2bf(o[qs][dt][3]*inv);
      *(ushort4*)(dst + dt*16) = pk;
    }
  }
}

extern "C" void kernel_launch(void* const* d_in, const int* in_sizes, int n_in,
                              void* d_out, int out_size, void* d_ws, size_t ws_size,
                              hipStream_t stream) {
  (void)in_sizes; (void)n_in; (void)out_size; (void)ws_size;
  const float* query = (const float*)d_in[0];
  const float* key   = (const float*)d_in[1];
  const float* value = (const float*)d_in[2];
  const float* Wq    = (const float*)d_in[3];
  const float* bq    = (const float*)d_in[4];
  const float* Wk    = (const float*)d_in[5];
  const float* bk    = (const float*)d_in[6];
  const float* Wv    = (const float*)d_in[7];
  const float* bv    = (const float*)d_in[8];
  const float* Wo    = (const float*)d_in[9];
  const float* bo    = (const float*)d_in[10];
  float* out = (float*)d_out;

  char* W = (char*)d_ws;
  u16*  qb     = (u16*) (W + 0);          // 16 MB  bf16 query [4096][2048]
  u16*  kb     = (u16*) (W + 16777216);   // 16 MB  bf16 key
  u16*  vb     = (u16*) (W + 33554432);   // 16 MB  bf16 value
  u16*  WqT    = (u16*) (W + 50331648);   //  8 MB  Wq^T  [2048][2048]
  u16*  WoT    = (u16*) (W + 58720256);   //  8 MB  Wo^T
  u16*  WkT    = (u16*) (W + 67108864);   // .5 MB  Wk^T  [128][2048]
  u16*  WvT    = (u16*) (W + 67633152);   // .5 MB  Wv^T
  u16*  Qp     = (u16*) (W + 68157440);   // 16 MB  Q proj bf16 [4096][2048]
  u16*  Kp     = (u16*) (W + 84934656);   //  1 MB  K proj bf16 [4096][128]
  u16*  VpT    = (u16*) (W + 85983232);   //  1 MB  V proj^T bf16 [B][128][2048]
  u16*  attnb  = (u16*) (W + 87031808);   // 16 MB  attention out bf16 [4096][2048]
  float* kvpart= (float*)(W + 103809024); // 16 MB  split-K partials [4][2][4096][128]

  convert3_kernel<<<8192, 256, 0, stream>>>(
      (const float4*)query, (const float4*)key, (const float4*)value,
      (ushort4*)qb, (ushort4*)kb, (ushort4*)vb);
  transpose_all<<<8704, 256, 0, stream>>>(Wq, Wo, Wk, Wv, WqT, WoT, WkT, WvT);
  proj_kernel<<<768, 256, 0, stream>>>(qb, kb, vb, WqT, WkT, WvT, bq, Qp, kvpart);
  kv_reduce_kernel<<<2048, 256, 0, stream>>>(kvpart, bk, bv, Kp, VpT);
  attn_kernel<<<dim3(8,32), 512, 0, stream>>>(Qp, Kp, VpT, attnb);
  oproj_kernel<<<dim3(32,16), 256, 0, stream>>>(attnb, WoT, bo, out);
}

// Round 7
// 412.793 us; speedup vs baseline: 1.0005x; 1.0005x over previous
//
#include <hip/hip_runtime.h>

// MQA: B=2, S=2048, D=2048, H=16, HD=128.  GEMMs bf16 MFMA 16x16x32, fp32 acc.
// v10: attention = v8 body (monolithic QK->softmax->PV, 1 barrier/kt, K+V
// double-buffered, merged K=32 PV, defer-max) restructured to 4-wave blocks:
//   QTILE=128 q-rows (4 waves x 32), KVBLK=64 keys, LDS 64 KB -> TWO
//   independent blocks per CU (launch_bounds(256,2)). Same total waves /
//   intensity / bytes as v8; the gain is cross-block drift: when one block
//   sits in its barrier drain, the other block's waves keep issuing.
// v9 lesson: intra-wave source reordering regressed (-7%) -> reverted.
// (Resubmit: round-6 bench was an infra failure; kernel never ran.)
// GEMM core unchanged; Q-proj + KV-proj fused; 4 transposes fused.

typedef unsigned short u16;
typedef __attribute__((ext_vector_type(8))) short bf16x8;   // 8 bf16 = 4 VGPR
typedef __attribute__((ext_vector_type(4))) short bf16x4;   // 4 bf16 = 2 VGPR
typedef __attribute__((ext_vector_type(4))) float f32x4;

#define D_MODEL 2048
#define SEQ     2048
#define NH      16
#define HD      128
#define BK      32

__device__ __forceinline__ u16 f2bf(float f){
  union { float f; unsigned u; } v; v.f = f;
  unsigned r = (v.u + 0x7FFFu + ((v.u >> 16) & 1u)) >> 16;  // RNE
  return (u16)r;
}

#if __has_builtin(__builtin_amdgcn_cvt_pk_bf16_f32)
__device__ __forceinline__ unsigned pack2bf(float a, float b){
  auto v = __builtin_amdgcn_cvt_pk_bf16_f32(a, b);
  unsigned u; __builtin_memcpy(&u, &v, 4); return u;
}
#else
__device__ __forceinline__ unsigned pack2bf(float a, float b){
  return (unsigned)f2bf(a) | ((unsigned)f2bf(b) << 16);
}
#endif

__device__ __forceinline__ void gll16(const void* g, void* l){
  __builtin_amdgcn_global_load_lds(
      (const __attribute__((address_space(1))) void*)g,
      (__attribute__((address_space(3))) void*)l, 16, 0, 0);
}

// ---------------- fp32 -> bf16 conversion of q,k,v ----------------
__global__ __launch_bounds__(256) void convert3_kernel(
    const float4* __restrict__ a, const float4* __restrict__ b, const float4* __restrict__ c,
    ushort4* __restrict__ oa, ushort4* __restrict__ ob, ushort4* __restrict__ oc){
  int i = blockIdx.x*256 + threadIdx.x;
  float4 va = a[i], vb = b[i], vc = c[i];
  ushort4 ra, rb, rc;
  ra.x=f2bf(va.x); ra.y=f2bf(va.y); ra.z=f2bf(va.z); ra.w=f2bf(va.w);
  rb.x=f2bf(vb.x); rb.y=f2bf(vb.y); rb.z=f2bf(vb.z); rb.w=f2bf(vb.w);
  rc.x=f2bf(vc.x); rc.y=f2bf(vc.y); rc.z=f2bf(vc.z); rc.w=f2bf(vc.w);
  oa[i]=ra; ob[i]=rb; oc[i]=rc;
}

// ---------------- all 4 weight transposes in one launch ----------------
__global__ __launch_bounds__(256) void transpose_all(
    const float* __restrict__ Wq, const float* __restrict__ Wo,
    const float* __restrict__ Wk, const float* __restrict__ Wv,
    u16* __restrict__ WqT, u16* __restrict__ WoT,
    u16* __restrict__ WkT, u16* __restrict__ WvT){
  __shared__ float tt[32][33];
  int id = blockIdx.x;
  const float* in; u16* outp; int C, bx, by;
  if (id < 4096)      { in=Wq; outp=WqT; C=2048; bx=id&63;        by=id>>6; }
  else if (id < 8192) { id-=4096; in=Wo; outp=WoT; C=2048; bx=id&63; by=id>>6; }
  else if (id < 8448) { id-=8192; in=Wk; outp=WkT; C=128;  bx=id&3;  by=id>>2; }
  else                { id-=8448; in=Wv; outp=WvT; C=128;  bx=id&3;  by=id>>2; }
  const int R = 2048;
  int c0 = bx*32, r0 = by*32;
  int tx = threadIdx.x & 31, ty = threadIdx.x >> 5;   // (32,8) flattened
  #pragma unroll
  for (int k=0;k<4;k++) tt[ty+k*8][tx] = in[(size_t)(r0+ty+k*8)*C + c0+tx];
  __syncthreads();
  #pragma unroll
  for (int k=0;k<4;k++) outp[(size_t)(c0+ty+k*8)*R + r0+tx] = f2bf(tt[tx][ty+k*8]);
}

// ---------------- double-buffered GEMM core: 1 barrier/iter ----------------
__device__ __forceinline__ void gemm_core_db(
    const u16* __restrict__ A, const u16* __restrict__ BT,
    int lda, int ldb, int m0, int n0, int kbeg, int kend,
    u16* As, u16* Bs, f32x4 acc[4][4])
{
  const int t = threadIdx.x;
  const int w = t >> 6, l = t & 63;
  const int wr = w >> 1, wc = w & 1;
  const int c16 = l & 15, q = l >> 4;
  const int srow = l >> 2;
  const int sc   = ((l & 3) ^ ((l >> 3) & 3)) * 8;

  int aoff[4], boff[4];
  #pragma unroll
  for (int mt=0;mt<4;mt++){
    int row = wr*64 + mt*16 + c16;
    aoff[mt] = row*BK + ((q ^ ((row>>1)&3))*8);
  }
  #pragma unroll
  for (int nt=0;nt<4;nt++){
    int row = wc*64 + nt*16 + c16;
    boff[nt] = row*BK + ((q ^ ((row>>1)&3))*8);
  }

  auto issue = [&](int k0, int buf){
    u16* Ad = As + buf*4096;
    u16* Bd = Bs + buf*4096;
    #pragma unroll
    for (int half=0; half<2; half++){
      int r = half*64 + w*16 + srow;
      gll16(A  + (size_t)(m0+r)*lda + k0 + sc, Ad + (half*64 + w*16)*BK);
      gll16(BT + (size_t)(n0+r)*ldb + k0 + sc, Bd + (half*64 + w*16)*BK);
    }
  };

  const int n = (kend - kbeg) / BK;
  issue(kbeg, 0);
  for (int i = 0; i < n; i++){
    __syncthreads();                       // tile i arrived; buf (i+1)&1 free
    if (i+1 < n) issue(kbeg + (i+1)*BK, (i+1)&1);
    const u16* Ab = As + (i&1)*4096;
    const u16* Bb = Bs + (i&1)*4096;
    bf16x8 af[4], bfr[4];
    #pragma unroll
    for (int mt=0;mt<4;mt++) af[mt]  = *(const bf16x8*)(Ab + aoff[mt]);
    #pragma unroll
    for (int nt=0;nt<4;nt++) bfr[nt] = *(const bf16x8*)(Bb + boff[nt]);
    #pragma unroll
    for (int mt=0;mt<4;mt++)
      #pragma unroll
      for (int nt=0;nt<4;nt++)
        acc[mt][nt] = __builtin_amdgcn_mfma_f32_16x16x32_bf16(af[mt], bfr[nt], acc[mt][nt], 0,0,0);
  }
}

// ---------------- fused Q-projection + K/V projection ----------------
__global__ __launch_bounds__(256) void proj_kernel(
    const u16* __restrict__ qb, const u16* __restrict__ kb, const u16* __restrict__ vb,
    const u16* __restrict__ WqT, const u16* __restrict__ WkT, const u16* __restrict__ WvT,
    const float* __restrict__ bq, u16* __restrict__ Qp, float* __restrict__ part)
{
  __shared__ u16 As[2*4096], Bs[2*4096];
  f32x4 acc[4][4];
  f32x4 z = {0.f,0.f,0.f,0.f};
  #pragma unroll
  for (int i=0;i<4;i++) for (int j=0;j<4;j++) acc[i][j] = z;
  const int t = threadIdx.x, w = t>>6, l = t&63, wr = w>>1, wc = w&1, c16 = l&15, q = l>>4;
  int id = blockIdx.x;
  if (id < 512){
    int m0 = (id & 31)*128, n0 = (id >> 5)*128;
    gemm_core_db(qb, WqT, 2048, 2048, m0, n0, 0, 2048, As, Bs, acc);
    #pragma unroll
    for (int mt=0;mt<4;mt++)
      #pragma unroll
      for (int nt=0;nt<4;nt++){
        int col = n0 + wc*64 + nt*16 + c16;
        float bv = bq[col];
        #pragma unroll
        for (int r=0;r<4;r++){
          int row = m0 + wr*64 + mt*16 + q*4 + r;
          Qp[(size_t)row*D_MODEL + col] = f2bf(acc[mt][nt][r] + bv);
        }
      }
  } else {
    int kvid = id - 512;
    int zi = kvid & 3, nb = (kvid >> 2) & 1, mi = kvid >> 3;
    const u16* Am = nb ? vb  : kb;
    const u16* Bm = nb ? WvT : WkT;
    gemm_core_db(Am, Bm, 2048, 2048, mi*128, 0, zi*512, zi*512+512, As, Bs, acc);
    float* dst = part + (size_t)(zi*2 + nb)*524288;   // [z][nb][4096][128]
    #pragma unroll
    for (int mt=0;mt<4;mt++)
      #pragma unroll
      for (int nt=0;nt<4;nt++){
        int col = wc*64 + nt*16 + c16;
        #pragma unroll
        for (int r=0;r<4;r++){
          int row = mi*128 + wr*64 + mt*16 + q*4 + r;
          dst[(size_t)row*128 + col] = acc[mt][nt][r];
        }
      }
  }
}

// ---------------- O-projection GEMM + bias, fp32 out ----------------
__global__ __launch_bounds__(256) void oproj_kernel(
    const u16* __restrict__ A, const u16* __restrict__ BT, const float* __restrict__ bias,
    float* __restrict__ C)
{
  __shared__ u16 As[2*4096], Bs[2*4096];
  f32x4 acc[4][4];
  f32x4 z = {0.f,0.f,0.f,0.f};
  #pragma unroll
  for (int i=0;i<4;i++) for (int j=0;j<4;j++) acc[i][j] = z;
  int m0 = blockIdx.x*128, n0 = blockIdx.y*128;
  gemm_core_db(A, BT, 2048, 2048, m0, n0, 0, 2048, As, Bs, acc);
  const int t = threadIdx.x, w = t>>6, l = t&63, wr = w>>1, wc = w&1, c16 = l&15, q = l>>4;
  #pragma unroll
  for (int mt=0;mt<4;mt++)
    #pragma unroll
    for (int nt=0;nt<4;nt++){
      int col = n0 + wc*64 + nt*16 + c16;
      float bv = bias[col];
      #pragma unroll
      for (int r=0;r<4;r++){
        int row = m0 + wr*64 + mt*16 + q*4 + r;
        C[(size_t)row*D_MODEL + col] = acc[mt][nt][r] + bv;
      }
    }
}

// ---------------- reduce split-K partials; Kp bf16 [4096][128], VpT bf16 [B][128][S] ----------------
__global__ __launch_bounds__(256) void kv_reduce_kernel(
    const float* __restrict__ part, const float* __restrict__ bk, const float* __restrict__ bv,
    u16* __restrict__ Kp, u16* __restrict__ VpT){
  int idx = blockIdx.x*256 + threadIdx.x;
  int d = idx & 127, sg = idx >> 7;
  float ka = 0.f, va = 0.f;
  #pragma unroll
  for (int zi=0; zi<4; zi++){
    ka += part[(size_t)(zi*2+0)*524288 + idx];
    va += part[(size_t)(zi*2+1)*524288 + idx];
  }
  Kp[idx] = f2bf(ka + bk[d]);
  int b = sg >> 11, sl = sg & 2047;
  VpT[(size_t)b*262144 + (size_t)d*2048 + sl] = f2bf(va + bv[d]);
}

// ---------------- flash attention v10 ----------------
// 4 waves x 32 q-rows (2 q-sets); QTILE=128, KVBLK=64; grid (16,32) = 512
// blocks = 2 independent blocks/CU (LDS 64 KB each). K+V double-buffered,
// 1 barrier per 64-key tile (32 iters). v8 body order. Defer-max slack 8.
// K LDS: Ks[64][128] chunk16 XOR-swz (ck ^ row&15). V LDS: Vs[128][64] (V^T)
// chunk8 XOR-swz (ck ^ d&7), pre-swizzled gll source + swizzled read.
// PV merged K=32 MFMA via lane-held k-permutation (exact; see v6).
__global__ __launch_bounds__(256, 2) void attn_kernel(
    const u16* __restrict__ Qp, const u16* __restrict__ Kp,
    const u16* __restrict__ VpT, u16* __restrict__ attnb){
  __shared__ u16 lds[32768];    // 64 KB: Ks 2x8192 u16 | Vs 2x8192 u16
  const int t = threadIdx.x;
  const int w = t >> 6, l = t & 63;    // w 0..3
  const int c16 = l & 15, q = l >> 4;

  const int qt = blockIdx.x;           // 0..15
  const int bh = blockIdx.y;           // 0..31
  const int b = bh >> 4, h = bh & 15;

  const u16* Qbase = Qp  + ((size_t)(b*SEQ + qt*128 + w*32))*D_MODEL + h*HD;
  const u16* Kbase = Kp  + (size_t)(b*SEQ)*HD;
  const u16* Vbase = VpT + (size_t)b*HD*SEQ;

  // staging coords: K row r = j*16 + kr (chunk16 = l&15); V row d = j*32 + vd0 (chunk8 = l&7)
  const int kr  = w*4 + (l >> 4);
  const int kpc = l & 15;
  const int vd0 = w*8 + (l >> 3);
  const int vpc = l & 7;

  // ---- prologue: stage K0+V0 into buf 0; Q frags global->reg ----
  #pragma unroll
  for (int j=0;j<4;j++){
    int r = j*16 + kr;
    gll16(Kbase + (size_t)r*HD + ((kpc ^ (r & 15))*8), lds + j*2048 + w*512);
  }
  #pragma unroll
  for (int j=0;j<4;j++){
    int d = j*32 + vd0;
    gll16(Vbase + (size_t)d*SEQ + ((vpc ^ (d & 7))*8), lds + 16384 + j*2048 + w*512);
  }
  bf16x8 qf[2][4];
  #pragma unroll
  for (int qs=0;qs<2;qs++)
    #pragma unroll
    for (int kk=0;kk<4;kk++)
      qf[qs][kk] = *(const bf16x8*)(Qbase + (size_t)(qs*16 + c16)*D_MODEL + (kk*4 + q)*8);
  __syncthreads();   // K0+V0 arrived

  f32x4 o[2][8];
  f32x4 z4 = {0.f,0.f,0.f,0.f};
  #pragma unroll
  for (int qs=0;qs<2;qs++) for (int dt=0;dt<8;dt++) o[qs][dt] = z4;
  float mrow[2] = {-1e30f, -1e30f};
  float lrow[2] = {0.f, 0.f};
  const float cs = 0.08838834764831845f * 1.4426950408889634f;  // (1/sqrt(128))*log2(e)

  for (int kt = 0; kt < 32; kt++){
    const int p = kt & 1;
    // issue glls for tile kt+1 into the idle buffer (p^1): its previous
    // readers (iter kt-1) were certified done by the last barrier.
    if (kt < 31){
      u16* Kd = lds + (p^1)*8192;
      u16* Vd = lds + 16384 + (p^1)*8192;
      #pragma unroll
      for (int j=0;j<4;j++){
        int r = j*16 + kr;
        gll16(Kbase + (size_t)((kt+1)*64 + r)*HD + ((kpc ^ (r & 15))*8), Kd + j*2048 + w*512);
      }
      #pragma unroll
      for (int j=0;j<4;j++){
        int d = j*32 + vd0;
        gll16(Vbase + (size_t)d*SEQ + (kt+1)*64 + ((vpc ^ (d & 7))*8), Vd + j*2048 + w*512);
      }
    }
    const u16* Ks = lds + p*8192;
    const u16* Vs = lds + 16384 + p*8192;

    // S^T = K Q^T : each kf LDS read feeds both q-sets. s[qs][kt8] covers
    // keys kt*64 + kt8*16 + 4q + r.
    f32x4 s[2][4];
    __builtin_amdgcn_s_setprio(1);
    #pragma unroll
    for (int kt8=0; kt8<4; kt8++){
      {
        bf16x8 kf = *(const bf16x8*)(Ks + (kt8*16 + c16)*128 + ((q ^ c16) & 15)*8);
        s[0][kt8] = __builtin_amdgcn_mfma_f32_16x16x32_bf16(kf, qf[0][0], z4, 0,0,0);
        s[1][kt8] = __builtin_amdgcn_mfma_f32_16x16x32_bf16(kf, qf[1][0], z4, 0,0,0);
      }
      #pragma unroll
      for (int kk=1;kk<4;kk++){
        int ch = kk*4 + q;
        bf16x8 kf = *(const bf16x8*)(Ks + (kt8*16 + c16)*128 + ((ch ^ c16) & 15)*8);
        s[0][kt8] = __builtin_amdgcn_mfma_f32_16x16x32_bf16(kf, qf[0][kk], s[0][kt8], 0,0,0);
        s[1][kt8] = __builtin_amdgcn_mfma_f32_16x16x32_bf16(kf, qf[1][kk], s[1][kt8], 0,0,0);
      }
    }
    __builtin_amdgcn_s_setprio(0);

    // online softmax (defer-max, slack 8 exponent units)
    float vmax[2];
    #pragma unroll
    for (int qs=0; qs<2; qs++){
      float x0 = fmaxf(fmaxf(s[qs][0][0],s[qs][0][1]), fmaxf(s[qs][0][2],s[qs][0][3]));
      float x1 = fmaxf(fmaxf(s[qs][1][0],s[qs][1][1]), fmaxf(s[qs][1][2],s[qs][1][3]));
      float x2 = fmaxf(fmaxf(s[qs][2][0],s[qs][2][1]), fmaxf(s[qs][2][2],s[qs][2][3]));
      float x3 = fmaxf(fmaxf(s[qs][3][0],s[qs][3][1]), fmaxf(s[qs][3][2],s[qs][3][3]));
      float vm = fmaxf(fmaxf(x0,x1), fmaxf(x2,x3));
      vm = fmaxf(vm, __shfl_xor(vm, 16));
      vm = fmaxf(vm, __shfl_xor(vm, 32));
      vmax[qs] = vm;
    }
    bool upd = ((vmax[0]-mrow[0])*cs > 8.f) || ((vmax[1]-mrow[1])*cs > 8.f);
    if (__any(upd)){                      // rare after tile 0
      #pragma unroll
      for (int qs=0; qs<2; qs++){
        float mnew = fmaxf(mrow[qs], vmax[qs]);
        float a = exp2f((mrow[qs]-mnew)*cs);
        mrow[qs] = mnew; lrow[qs] *= a;
        #pragma unroll
        for (int dt=0;dt<8;dt++)
          #pragma unroll
          for (int r=0;r<4;r++) o[qs][dt][r] *= a;
      }
    }
    union PU { unsigned u[4]; bf16x8 v; } P32[2][2];
    #pragma unroll
    for (int qs=0; qs<2; qs++){
      float mc = mrow[qs]*cs;
      float rsum = 0.f;
      #pragma unroll
      for (int kt8=0;kt8<4;kt8++){
        float p0 = exp2f(__builtin_fmaf(s[qs][kt8][0], cs, -mc));
        float p1 = exp2f(__builtin_fmaf(s[qs][kt8][1], cs, -mc));
        float p2 = exp2f(__builtin_fmaf(s[qs][kt8][2], cs, -mc));
        float p3 = exp2f(__builtin_fmaf(s[qs][kt8][3], cs, -mc));
        s[qs][kt8][0]=p0; s[qs][kt8][1]=p1; s[qs][kt8][2]=p2; s[qs][kt8][3]=p3;
        rsum += (p0+p1)+(p2+p3);
      }
      rsum += __shfl_xor(rsum, 16);
      rsum += __shfl_xor(rsum, 32);
      lrow[qs] += rsum;
      // P32[qs][kb]: slots 0..3 = keys 32kb+4q+r, slots 4..7 = keys 32kb+16+4q+r
      P32[qs][0].u[0] = pack2bf(s[qs][0][0], s[qs][0][1]);
      P32[qs][0].u[1] = pack2bf(s[qs][0][2], s[qs][0][3]);
      P32[qs][0].u[2] = pack2bf(s[qs][1][0], s[qs][1][1]);
      P32[qs][0].u[3] = pack2bf(s[qs][1][2], s[qs][1][3]);
      P32[qs][1].u[0] = pack2bf(s[qs][2][0], s[qs][2][1]);
      P32[qs][1].u[1] = pack2bf(s[qs][2][2], s[qs][2][3]);
      P32[qs][1].u[2] = pack2bf(s[qs][3][0], s[qs][3][1]);
      P32[qs][1].u[3] = pack2bf(s[qs][3][2], s[qs][3][3]);
    }

    // O^T += V^T P^T : A = V^T frags in the lane-held permuted k order.
    // Vs row d (64 keys = 8 chunks), logical chunk ck at physical (ck^(d&7)).
    __builtin_amdgcn_s_setprio(1);
    #pragma unroll
    for (int kb=0; kb<2; kb++){
      int ca = 4*kb + (q>>1);       // chunk for k=32kb+4q (half q&1)
      int cb = ca + 2;              // chunk for k=32kb+16+4q
      #pragma unroll
      for (int dt=0; dt<8; dt++){
        int d = dt*16 + c16;
        union VU { bf16x4 hh[2]; bf16x8 v; } vf;
        vf.hh[0] = *(const bf16x4*)(Vs + d*64 + ((ca ^ (d&7)) & 7)*8 + (q&1)*4);
        vf.hh[1] = *(const bf16x4*)(Vs + d*64 + ((cb ^ (d&7)) & 7)*8 + (q&1)*4);
        o[0][dt] = __builtin_amdgcn_mfma_f32_16x16x32_bf16(vf.v, P32[0][kb].v, o[0][dt], 0,0,0);
        o[1][dt] = __builtin_amdgcn_mfma_f32_16x16x32_bf16(vf.v, P32[1][kb].v, o[1][dt], 0,0,0);
      }
    }
    __builtin_amdgcn_s_setprio(0);
    __syncthreads();   // drains tile kt+1 glls (issued a full body ago) and
                       // certifies all waves done reading buf p
  }

  // normalize + write: lane holds O[q=c16+16qs][d=dt*16+quad*4+r]
  #pragma unroll
  for (int qs=0;qs<2;qs++){
    float inv = 1.f / lrow[qs];
    int qrow = qt*128 + w*32 + qs*16 + c16;
    u16* dst = attnb + ((size_t)(b*SEQ) + qrow)*D_MODEL + h*HD + q*4;
    #pragma unroll
    for (int dt=0;dt<8;dt++){
      ushort4 pk;
      pk.x = f2bf(o[qs][dt][0]*inv);
      pk.y = f2bf(o[qs][dt][1]*inv);
      pk.z = f2bf(o[qs][dt][2]*inv);
      pk.w = f2bf(o[qs][dt][3]*inv);
      *(ushort4*)(dst + dt*16) = pk;
    }
  }
}

extern "C" void kernel_launch(void* const* d_in, const int* in_sizes, int n_in,
                              void* d_out, int out_size, void* d_ws, size_t ws_size,
                              hipStream_t stream) {
  (void)in_sizes; (void)n_in; (void)out_size; (void)ws_size;
  const float* query = (const float*)d_in[0];
  const float* key   = (const float*)d_in[1];
  const float* value = (const float*)d_in[2];
  const float* Wq    = (const float*)d_in[3];
  const float* bq    = (const float*)d_in[4];
  const float* Wk    = (const float*)d_in[5];
  const float* bk    = (const float*)d_in[6];
  const float* Wv    = (const float*)d_in[7];
  const float* bv    = (const float*)d_in[8];
  const float* Wo    = (const float*)d_in[9];
  const float* bo    = (const float*)d_in[10];
  float* out = (float*)d_out;

  char* W = (char*)d_ws;
  u16*  qb     = (u16*) (W + 0);          // 16 MB  bf16 query [4096][2048]
  u16*  kb     = (u16*) (W + 16777216);   // 16 MB  bf16 key
  u16*  vb     = (u16*) (W + 33554432);   // 16 MB  bf16 value
  u16*  WqT    = (u16*) (W + 50331648);   //  8 MB  Wq^T  [2048][2048]
  u16*  WoT    = (u16*) (W + 58720256);   //  8 MB  Wo^T
  u16*  WkT    = (u16*) (W + 67108864);   // .5 MB  Wk^T  [128][2048]
  u16*  WvT    = (u16*) (W + 67633152);   // .5 MB  Wv^T
  u16*  Qp     = (u16*) (W + 68157440);   // 16 MB  Q proj bf16 [4096][2048]
  u16*  Kp     = (u16*) (W + 84934656);   //  1 MB  K proj bf16 [4096][128]
  u16*  VpT    = (u16*) (W + 85983232);   //  1 MB  V proj^T bf16 [B][128][2048]
  u16*  attnb  = (u16*) (W + 87031808);   // 16 MB  attention out bf16 [4096][2048]
  float* kvpart= (float*)(W + 103809024); // 16 MB  split-K partials [4][2][4096][128]

  convert3_kernel<<<8192, 256, 0, stream>>>(
      (const float4*)query, (const float4*)key, (const float4*)value,
      (ushort4*)qb, (ushort4*)kb, (ushort4*)vb);
  transpose_all<<<8704, 256, 0, stream>>>(Wq, Wo, Wk, Wv, WqT, WoT, WkT, WvT);
  proj_kernel<<<768, 256, 0, stream>>>(qb, kb, vb, WqT, WkT, WvT, bq, Qp, kvpart);
  kv_reduce_kernel<<<2048, 256, 0, stream>>>(kvpart, bk, bv, Kp, VpT);
  attn_kernel<<<dim3(16,32), 256, 0, stream>>>(Qp, Kp, VpT, attnb);
  oproj_kernel<<<dim3(32,16), 256, 0, stream>>>(attnb, WoT, bo, out);
}

// Round 8
// 406.900 us; speedup vs baseline: 1.0150x; 1.0145x over previous
//
#include <hip/hip_runtime.h>

// MQA: B=2, S=2048, D=2048, H=16, HD=128.  GEMMs bf16 MFMA 16x16x32, fp32 acc.
// v11: attn = v8 (8 waves x 32 q-rows, K+V dbuf 128KB, 1 barrier/kt, merged
// K=32 PV — best measured 117us) + defer-max slack 8 + C=z4 s-init.
// Non-attn side (~290us, ~2x attn) attacked: XCD-chunk swizzle on proj-Q and
// oproj (each XCD owns an m-slab -> A panel L2-resident, ~10MB/XCD vs ~24MB);
// convert3+transpose fused into one prep launch (one less gap).
// v9/v10 lessons: intra-wave reordering and 2-block/CU splitting both null.

typedef unsigned short u16;
typedef __attribute__((ext_vector_type(8))) short bf16x8;   // 8 bf16 = 4 VGPR
typedef __attribute__((ext_vector_type(4))) short bf16x4;   // 4 bf16 = 2 VGPR
typedef __attribute__((ext_vector_type(4))) float f32x4;

#define D_MODEL 2048
#define SEQ     2048
#define NH      16
#define HD      128
#define BK      32

__device__ __forceinline__ u16 f2bf(float f){
  union { float f; unsigned u; } v; v.f = f;
  unsigned r = (v.u + 0x7FFFu + ((v.u >> 16) & 1u)) >> 16;  // RNE
  return (u16)r;
}

#if __has_builtin(__builtin_amdgcn_cvt_pk_bf16_f32)
__device__ __forceinline__ unsigned pack2bf(float a, float b){
  auto v = __builtin_amdgcn_cvt_pk_bf16_f32(a, b);
  unsigned u; __builtin_memcpy(&u, &v, 4); return u;
}
#else
__device__ __forceinline__ unsigned pack2bf(float a, float b){
  return (unsigned)f2bf(a) | ((unsigned)f2bf(b) << 16);
}
#endif

__device__ __forceinline__ void gll16(const void* g, void* l){
  __builtin_amdgcn_global_load_lds(
      (const __attribute__((address_space(1))) void*)g,
      (__attribute__((address_space(3))) void*)l, 16, 0, 0);
}

// ---------------- fused prep: fp32->bf16 convert of q,k,v + 4 transposes ----
// blocks 0..8191: convert (each handles 256 float4 per input).
// blocks 8192..16895: weight transposes (Wq, Wo, Wk, Wv).
__global__ __launch_bounds__(256) void prep_kernel(
    const float4* __restrict__ qa, const float4* __restrict__ ka, const float4* __restrict__ va,
    ushort4* __restrict__ oq, ushort4* __restrict__ ok, ushort4* __restrict__ ov,
    const float* __restrict__ Wq, const float* __restrict__ Wo,
    const float* __restrict__ Wk, const float* __restrict__ Wv,
    u16* __restrict__ WqT, u16* __restrict__ WoT,
    u16* __restrict__ WkT, u16* __restrict__ WvT){
  __shared__ float tt[32][33];
  int bid = blockIdx.x;
  if (bid < 8192){
    int i = bid*256 + threadIdx.x;
    float4 a = qa[i], b = ka[i], c = va[i];
    ushort4 ra, rb, rc;
    ra.x=f2bf(a.x); ra.y=f2bf(a.y); ra.z=f2bf(a.z); ra.w=f2bf(a.w);
    rb.x=f2bf(b.x); rb.y=f2bf(b.y); rb.z=f2bf(b.z); rb.w=f2bf(b.w);
    rc.x=f2bf(c.x); rc.y=f2bf(c.y); rc.z=f2bf(c.z); rc.w=f2bf(c.w);
    oq[i]=ra; ok[i]=rb; ov[i]=rc;
    return;
  }
  int id = bid - 8192;
  const float* in; u16* outp; int C, bx, by;
  if (id < 4096)      { in=Wq; outp=WqT; C=2048; bx=id&63;        by=id>>6; }
  else if (id < 8192) { id-=4096; in=Wo; outp=WoT; C=2048; bx=id&63; by=id>>6; }
  else if (id < 8448) { id-=8192; in=Wk; outp=WkT; C=128;  bx=id&3;  by=id>>2; }
  else                { id-=8448; in=Wv; outp=WvT; C=128;  bx=id&3;  by=id>>2; }
  const int R = 2048;
  int c0 = bx*32, r0 = by*32;
  int tx = threadIdx.x & 31, ty = threadIdx.x >> 5;   // (32,8) flattened
  #pragma unroll
  for (int k=0;k<4;k++) tt[ty+k*8][tx] = in[(size_t)(r0+ty+k*8)*C + c0+tx];
  __syncthreads();
  #pragma unroll
  for (int k=0;k<4;k++) outp[(size_t)(c0+ty+k*8)*R + r0+tx] = f2bf(tt[tx][ty+k*8]);
}

// ---------------- double-buffered GEMM core: 1 barrier/iter ----------------
__device__ __forceinline__ void gemm_core_db(
    const u16* __restrict__ A, const u16* __restrict__ BT,
    int lda, int ldb, int m0, int n0, int kbeg, int kend,
    u16* As, u16* Bs, f32x4 acc[4][4])
{
  const int t = threadIdx.x;
  const int w = t >> 6, l = t & 63;
  const int wr = w >> 1, wc = w & 1;
  const int c16 = l & 15, q = l >> 4;
  const int srow = l >> 2;
  const int sc   = ((l & 3) ^ ((l >> 3) & 3)) * 8;

  int aoff[4], boff[4];
  #pragma unroll
  for (int mt=0;mt<4;mt++){
    int row = wr*64 + mt*16 + c16;
    aoff[mt] = row*BK + ((q ^ ((row>>1)&3))*8);
  }
  #pragma unroll
  for (int nt=0;nt<4;nt++){
    int row = wc*64 + nt*16 + c16;
    boff[nt] = row*BK + ((q ^ ((row>>1)&3))*8);
  }

  auto issue = [&](int k0, int buf){
    u16* Ad = As + buf*4096;
    u16* Bd = Bs + buf*4096;
    #pragma unroll
    for (int half=0; half<2; half++){
      int r = half*64 + w*16 + srow;
      gll16(A  + (size_t)(m0+r)*lda + k0 + sc, Ad + (half*64 + w*16)*BK);
      gll16(BT + (size_t)(n0+r)*ldb + k0 + sc, Bd + (half*64 + w*16)*BK);
    }
  };

  const int n = (kend - kbeg) / BK;
  issue(kbeg, 0);
  for (int i = 0; i < n; i++){
    __syncthreads();                       // tile i arrived; buf (i+1)&1 free
    if (i+1 < n) issue(kbeg + (i+1)*BK, (i+1)&1);
    const u16* Ab = As + (i&1)*4096;
    const u16* Bb = Bs + (i&1)*4096;
    bf16x8 af[4], bfr[4];
    #pragma unroll
    for (int mt=0;mt<4;mt++) af[mt]  = *(const bf16x8*)(Ab + aoff[mt]);
    #pragma unroll
    for (int nt=0;nt<4;nt++) bfr[nt] = *(const bf16x8*)(Bb + boff[nt]);
    #pragma unroll
    for (int mt=0;mt<4;mt++)
      #pragma unroll
      for (int nt=0;nt<4;nt++)
        acc[mt][nt] = __builtin_amdgcn_mfma_f32_16x16x32_bf16(af[mt], bfr[nt], acc[mt][nt], 0,0,0);
  }
}

// ---------------- fused Q-projection + K/V projection ----------------
// Q-part uses XCD-chunk swizzle: dispatch order round-robins blockIdx across
// XCDs; mapping x=id%8, j=id/8, mi=4x+(j&3), n=j>>2 gives XCD x the m-slab
// [4x,4x+4) -> its A panel (2MB) stays L2-resident while B streams.
__global__ __launch_bounds__(256) void proj_kernel(
    const u16* __restrict__ qb, const u16* __restrict__ kb, const u16* __restrict__ vb,
    const u16* __restrict__ WqT, const u16* __restrict__ WkT, const u16* __restrict__ WvT,
    const float* __restrict__ bq, u16* __restrict__ Qp, float* __restrict__ part)
{
  __shared__ u16 As[2*4096], Bs[2*4096];
  f32x4 acc[4][4];
  f32x4 z = {0.f,0.f,0.f,0.f};
  #pragma unroll
  for (int i=0;i<4;i++) for (int j=0;j<4;j++) acc[i][j] = z;
  const int t = threadIdx.x, w = t>>6, l = t&63, wr = w>>1, wc = w&1, c16 = l&15, q = l>>4;
  int id = blockIdx.x;
  if (id < 512){
    int x = id & 7, j = id >> 3;          // bijective XCD-chunk swizzle
    int m0 = (x*4 + (j & 3))*128, n0 = (j >> 2)*128;
    gemm_core_db(qb, WqT, 2048, 2048, m0, n0, 0, 2048, As, Bs, acc);
    #pragma unroll
    for (int mt=0;mt<4;mt++)
      #pragma unroll
      for (int nt=0;nt<4;nt++){
        int col = n0 + wc*64 + nt*16 + c16;
        float bv = bq[col];
        #pragma unroll
        for (int r=0;r<4;r++){
          int row = m0 + wr*64 + mt*16 + q*4 + r;
          Qp[(size_t)row*D_MODEL + col] = f2bf(acc[mt][nt][r] + bv);
        }
      }
  } else {
    int kvid = id - 512;
    int zi = kvid & 3, nb = (kvid >> 2) & 1, mi = kvid >> 3;
    const u16* Am = nb ? vb  : kb;
    const u16* Bm = nb ? WvT : WkT;
    gemm_core_db(Am, Bm, 2048, 2048, mi*128, 0, zi*512, zi*512+512, As, Bs, acc);
    float* dst = part + (size_t)(zi*2 + nb)*524288;   // [z][nb][4096][128]
    #pragma unroll
    for (int mt=0;mt<4;mt++)
      #pragma unroll
      for (int nt=0;nt<4;nt++){
        int col = wc*64 + nt*16 + c16;
        #pragma unroll
        for (int r=0;r<4;r++){
          int row = mi*128 + wr*64 + mt*16 + q*4 + r;
          dst[(size_t)row*128 + col] = acc[mt][nt][r];
        }
      }
  }
}

// ---------------- O-projection GEMM + bias, fp32 out (XCD-chunk swizzle) ----
__global__ __launch_bounds__(256) void oproj_kernel(
    const u16* __restrict__ A, const u16* __restrict__ BT, const float* __restrict__ bias,
    float* __restrict__ C)
{
  __shared__ u16 As[2*4096], Bs[2*4096];
  f32x4 acc[4][4];
  f32x4 z = {0.f,0.f,0.f,0.f};
  #pragma unroll
  for (int i=0;i<4;i++) for (int j=0;j<4;j++) acc[i][j] = z;
  int id = blockIdx.x;
  int x = id & 7, j = id >> 3;            // bijective XCD-chunk swizzle
  int m0 = (x*4 + (j & 3))*128, n0 = (j >> 2)*128;
  gemm_core_db(A, BT, 2048, 2048, m0, n0, 0, 2048, As, Bs, acc);
  const int t = threadIdx.x, w = t>>6, l = t&63, wr = w>>1, wc = w&1, c16 = l&15, q = l>>4;
  #pragma unroll
  for (int mt=0;mt<4;mt++)
    #pragma unroll
    for (int nt=0;nt<4;nt++){
      int col = n0 + wc*64 + nt*16 + c16;
      float bv = bias[col];
      #pragma unroll
      for (int r=0;r<4;r++){
        int row = m0 + wr*64 + mt*16 + q*4 + r;
        C[(size_t)row*D_MODEL + col] = acc[mt][nt][r] + bv;
      }
    }
}

// ---------------- reduce split-K partials; Kp bf16 [4096][128], VpT bf16 [B][128][S] ----------------
__global__ __launch_bounds__(256) void kv_reduce_kernel(
    const float* __restrict__ part, const float* __restrict__ bk, const float* __restrict__ bv,
    u16* __restrict__ Kp, u16* __restrict__ VpT){
  int idx = blockIdx.x*256 + threadIdx.x;
  int d = idx & 127, sg = idx >> 7;
  float ka = 0.f, va = 0.f;
  #pragma unroll
  for (int zi=0; zi<4; zi++){
    ka += part[(size_t)(zi*2+0)*524288 + idx];
    va += part[(size_t)(zi*2+1)*524288 + idx];
  }
  Kp[idx] = f2bf(ka + bk[d]);
  int b = sg >> 11, sl = sg & 2047;
  VpT[(size_t)b*262144 + (size_t)d*2048 + sl] = f2bf(va + bv[d]);
}

// ---------------- flash attention v11 (v8 + defer-max + z4 s-init) ----------
// 8 waves x 32 q-rows (2 q-sets); grid (8,32) = 256 blocks = 1/CU.
// K AND V double-buffered: LDS 128 KB. ONE barrier per 128-key tile: at iter
// top, issue all 8 glls for tile u+1 into buffer p^1; body runs barrier-free;
// end barrier drains loads issued a full body ago. Defer-max slack 8: skip
// m/alpha/O-rescale unless any lane's tile-max grows >8 exponent units.
__global__ __launch_bounds__(512, 2) void attn_kernel(
    const u16* __restrict__ Qp, const u16* __restrict__ Kp,
    const u16* __restrict__ VpT, u16* __restrict__ attnb){
  __shared__ u16 lds[65536];    // 128 KB
  const int t = threadIdx.x;
  const int w = t >> 6, l = t & 63;
  const int c16 = l & 15, q = l >> 4;

  const int qt = blockIdx.x;           // 0..7
  const int bh = blockIdx.y;           // 0..31
  const int b = bh >> 4, h = bh & 15;

  const u16* Qbase = Qp  + ((size_t)(b*SEQ + qt*256 + w*32))*D_MODEL + h*HD;
  const u16* Kbase = Kp  + (size_t)(b*SEQ)*HD;
  const u16* Vbase = VpT + (size_t)b*HD*SEQ;

  const int sr = w*4 + (l >> 4);       // staging row within 32-row group
  // ---- prologue: issue K0+V0 glls; Q frags global->reg ----
  #pragma unroll
  for (int j=0;j<4;j++){
    int r = j*32 + sr;
    int g = (l & 15) ^ (r & 15);
    gll16(Kbase + (size_t)r*HD + g*8, lds + j*4096 + w*512);
  }
  #pragma unroll
  for (int j=0;j<4;j++){
    int d = j*32 + sr;
    int g = (l & 15) ^ (d & 15);
    gll16(Vbase + (size_t)d*SEQ + g*8, lds + 32768 + j*4096 + w*512);
  }
  bf16x8 qf[2][4];
  #pragma unroll
  for (int qs=0;qs<2;qs++)
    #pragma unroll
    for (int kk=0;kk<4;kk++)
      qf[qs][kk] = *(const bf16x8*)(Qbase + (size_t)(qs*16 + c16)*D_MODEL + (kk*4 + q)*8);
  __syncthreads();   // K0+V0 arrived

  f32x4 o[2][8];
  f32x4 z4 = {0.f,0.f,0.f,0.f};
  #pragma unroll
  for (int qs=0;qs<2;qs++) for (int dt=0;dt<8;dt++) o[qs][dt] = z4;
  float mrow[2] = {-1e30f, -1e30f};
  float lrow[2] = {0.f, 0.f};
  const float cs = 0.08838834764831845f * 1.4426950408889634f;  // (1/sqrt(128))*log2(e)

  for (int kt = 0; kt < 16; kt++){
    const int p = kt & 1;
    // issue ALL glls for tile kt+1 into the idle buffer (p^1)
    if (kt < 15){
      u16* Kd = lds + (p^1)*16384;
      u16* Vd = lds + 32768 + (p^1)*16384;
      #pragma unroll
      for (int j=0;j<4;j++){
        int r = j*32 + sr;
        int g = (l & 15) ^ (r & 15);
        gll16(Kbase + (size_t)((kt+1)*128 + r)*HD + g*8, Kd + j*4096 + w*512);
      }
      #pragma unroll
      for (int j=0;j<4;j++){
        int d = j*32 + sr;
        int g = (l & 15) ^ (d & 15);
        gll16(Vbase + (size_t)d*SEQ + (kt+1)*128 + g*8, Vd + j*4096 + w*512);
      }
    }
    const u16* Ks = lds + p*16384;
    const u16* Vs = lds + 32768 + p*16384;

    // S^T = K Q^T : each kf LDS read feeds both q-sets; kk==0 uses C=z4
    f32x4 s[2][8];
    __builtin_amdgcn_s_setprio(1);
    #pragma unroll
    for (int kt8=0; kt8<8; kt8++){
      {
        bf16x8 kf = *(const bf16x8*)(Ks + (kt8*16 + c16)*128 + ((q ^ c16) & 15)*8);
        s[0][kt8] = __builtin_amdgcn_mfma_f32_16x16x32_bf16(kf, qf[0][0], z4, 0,0,0);
        s[1][kt8] = __builtin_amdgcn_mfma_f32_16x16x32_bf16(kf, qf[1][0], z4, 0,0,0);
      }
      #pragma unroll
      for (int kk=1;kk<4;kk++){
        int ch = kk*4 + q;
        bf16x8 kf = *(const bf16x8*)(Ks + (kt8*16 + c16)*128 + ((ch ^ c16) & 15)*8);
        s[0][kt8] = __builtin_amdgcn_mfma_f32_16x16x32_bf16(kf, qf[0][kk], s[0][kt8], 0,0,0);
        s[1][kt8] = __builtin_amdgcn_mfma_f32_16x16x32_bf16(kf, qf[1][kk], s[1][kt8], 0,0,0);
      }
    }
    __builtin_amdgcn_s_setprio(0);

    // online softmax with defer-max (slack 8 exponent units)
    float vmax[2];
    #pragma unroll
    for (int qs=0; qs<2; qs++){
      float xx[8];
      #pragma unroll
      for (int kt8=0;kt8<8;kt8++)
        xx[kt8] = fmaxf(fmaxf(s[qs][kt8][0],s[qs][kt8][1]), fmaxf(s[qs][kt8][2],s[qs][kt8][3]));
      float vm = fmaxf(fmaxf(fmaxf(xx[0],xx[1]),fmaxf(xx[2],xx[3])),
                       fmaxf(fmaxf(xx[4],xx[5]),fmaxf(xx[6],xx[7])));
      vm = fmaxf(vm, __shfl_xor(vm, 16));
      vm = fmaxf(vm, __shfl_xor(vm, 32));
      vmax[qs] = vm;
    }
    bool upd = ((vmax[0]-mrow[0])*cs > 8.f) || ((vmax[1]-mrow[1])*cs > 8.f);
    if (__any(upd)){                      // rare after tile 0
      #pragma unroll
      for (int qs=0; qs<2; qs++){
        float mnew = fmaxf(mrow[qs], vmax[qs]);
        float a = exp2f((mrow[qs]-mnew)*cs);
        mrow[qs] = mnew; lrow[qs] *= a;
        #pragma unroll
        for (int dt=0;dt<8;dt++)
          #pragma unroll
          for (int r=0;r<4;r++) o[qs][dt][r] *= a;
      }
    }
    union PU { unsigned u[4]; bf16x8 v; } P32[2][4];
    #pragma unroll
    for (int qs=0; qs<2; qs++){
      float mc = mrow[qs]*cs;
      float rsum = 0.f;
      #pragma unroll
      for (int kt8=0;kt8<8;kt8++){
        float p0 = exp2f(__builtin_fmaf(s[qs][kt8][0], cs, -mc));
        float p1 = exp2f(__builtin_fmaf(s[qs][kt8][1], cs, -mc));
        float p2 = exp2f(__builtin_fmaf(s[qs][kt8][2], cs, -mc));
        float p3 = exp2f(__builtin_fmaf(s[qs][kt8][3], cs, -mc));
        s[qs][kt8][0]=p0; s[qs][kt8][1]=p1; s[qs][kt8][2]=p2; s[qs][kt8][3]=p3;
        rsum += (p0+p1)+(p2+p3);
      }
      rsum += __shfl_xor(rsum, 16);
      rsum += __shfl_xor(rsum, 32);
      lrow[qs] += rsum;
      // P32[qs][kb]: slots 0..3 = keys 32kb+4q+r, slots 4..7 = keys 32kb+16+4q+r
      #pragma unroll
      for (int kb=0;kb<4;kb++){
        P32[qs][kb].u[0] = pack2bf(s[qs][2*kb][0],   s[qs][2*kb][1]);
        P32[qs][kb].u[1] = pack2bf(s[qs][2*kb][2],   s[qs][2*kb][3]);
        P32[qs][kb].u[2] = pack2bf(s[qs][2*kb+1][0], s[qs][2*kb+1][1]);
        P32[qs][kb].u[3] = pack2bf(s[qs][2*kb+1][2], s[qs][2*kb+1][3]);
      }
    }

    // O^T += V^T P^T : each vf LDS read feeds both q-sets
    __builtin_amdgcn_s_setprio(1);
    #pragma unroll
    for (int kb=0; kb<4; kb++){
      int ca = 4*kb + (q>>1);       // chunk for k=32kb+4q (half q&1)
      int cb = ca + 2;              // chunk for k=32kb+16+4q
      #pragma unroll
      for (int dt=0; dt<8; dt++){
        int d = dt*16 + c16;
        union VU { bf16x4 hh[2]; bf16x8 v; } vf;
        vf.hh[0] = *(const bf16x4*)(Vs + d*128 + ((ca ^ c16) & 15)*8 + (q&1)*4);
        vf.hh[1] = *(const bf16x4*)(Vs + d*128 + ((cb ^ c16) & 15)*8 + (q&1)*4);
        o[0][dt] = __builtin_amdgcn_mfma_f32_16x16x32_bf16(vf.v, P32[0][kb].v, o[0][dt], 0,0,0);
        o[1][dt] = __builtin_amdgcn_mfma_f32_16x16x32_bf16(vf.v, P32[1][kb].v, o[1][dt], 0,0,0);
      }
    }
    __builtin_amdgcn_s_setprio(0);
    __syncthreads();   // drains tile kt+1 glls; certifies buf p readers done
  }

  // normalize + write: lane holds O[q=c16+16qs][d=dt*16+quad*4+r]
  #pragma unroll
  for (int qs=0;qs<2;qs++){
    float inv = 1.f / lrow[qs];
    int qrow = qt*256 + w*32 + qs*16 + c16;
    u16* dst = attnb + ((size_t)(b*SEQ) + qrow)*D_MODEL + h*HD + q*4;
    #pragma unroll
    for (int dt=0;dt<8;dt++){
      ushort4 pk;
      pk.x = f2bf(o[qs][dt][0]*inv);
      pk.y = f2bf(o[qs][dt][1]*inv);
      pk.z = f2bf(o[qs][dt][2]*inv);
      pk.w = f2bf(o[qs][dt][3]*inv);
      *(ushort4*)(dst + dt*16) = pk;
    }
  }
}

extern "C" void kernel_launch(void* const* d_in, const int* in_sizes, int n_in,
                              void* d_out, int out_size, void* d_ws, size_t ws_size,
                              hipStream_t stream) {
  (void)in_sizes; (void)n_in; (void)out_size; (void)ws_size;
  const float* query = (const float*)d_in[0];
  const float* key   = (const float*)d_in[1];
  const float* value = (const float*)d_in[2];
  const float* Wq    = (const float*)d_in[3];
  const float* bq    = (const float*)d_in[4];
  const float* Wk    = (const float*)d_in[5];
  const float* bk    = (const float*)d_in[6];
  const float* Wv    = (const float*)d_in[7];
  const float* bv    = (const float*)d_in[8];
  const float* Wo    = (const float*)d_in[9];
  const float* bo    = (const float*)d_in[10];
  float* out = (float*)d_out;

  char* W = (char*)d_ws;
  u16*  qb     = (u16*) (W + 0);          // 16 MB  bf16 query [4096][2048]
  u16*  kb     = (u16*) (W + 16777216);   // 16 MB  bf16 key
  u16*  vb     = (u16*) (W + 33554432);   // 16 MB  bf16 value
  u16*  WqT    = (u16*) (W + 50331648);   //  8 MB  Wq^T  [2048][2048]
  u16*  WoT    = (u16*) (W + 58720256);   //  8 MB  Wo^T
  u16*  WkT    = (u16*) (W + 67108864);   // .5 MB  Wk^T  [128][2048]
  u16*  WvT    = (u16*) (W + 67633152);   // .5 MB  Wv^T
  u16*  Qp     = (u16*) (W + 68157440);   // 16 MB  Q proj bf16 [4096][2048]
  u16*  Kp     = (u16*) (W + 84934656);   //  1 MB  K proj bf16 [4096][128]
  u16*  VpT    = (u16*) (W + 85983232);   //  1 MB  V proj^T bf16 [B][128][2048]
  u16*  attnb  = (u16*) (W + 87031808);   // 16 MB  attention out bf16 [4096][2048]
  float* kvpart= (float*)(W + 103809024); // 16 MB  split-K partials [4][2][4096][128]

  prep_kernel<<<16896, 256, 0, stream>>>(
      (const float4*)query, (const float4*)key, (const float4*)value,
      (ushort4*)qb, (ushort4*)kb, (ushort4*)vb,
      Wq, Wo, Wk, Wv, WqT, WoT, WkT, WvT);
  proj_kernel<<<768, 256, 0, stream>>>(qb, kb, vb, WqT, WkT, WvT, bq, Qp, kvpart);
  kv_reduce_kernel<<<2048, 256, 0, stream>>>(kvpart, bk, bv, Kp, VpT);
  attn_kernel<<<dim3(8,32), 512, 0, stream>>>(Qp, Kp, VpT, attnb);
  oproj_kernel<<<512, 256, 0, stream>>>(attnb, WoT, bo, out);
}

// Round 9
// 404.299 us; speedup vs baseline: 1.0215x; 1.0064x over previous
//
#include <hip/hip_runtime.h>

// MQA: B=2, S=2048, D=2048, H=16, HD=128.  GEMMs bf16 MFMA 16x16x32, fp32 acc.
// v12: single variable vs v11 — GEMM core depth-3 prefetch with counted vmcnt:
// 3 LDS buffers (48KB), glls for tile i+2 issued at iter i, barrier is
// s_waitcnt vmcnt(4) + raw s_barrier (tile i+2's loads stay in flight across
// the barrier; only tile i+1's are awaited). Depth-2 (__syncthreads) drains
// ALL glls every iter -> HBM latency on the critical path (guide: depth-2
// variants all ~880 ceiling; counted-vmcnt depth-3 is T4's +38-73% lever).
// attn = v11 (best, 114us): 8w x 32q, K+V dbuf, 1 barrier/kt, merged K=32 PV,
// defer-max slack 8. prep fusion + XCD-chunk swizzle kept.

typedef unsigned short u16;
typedef __attribute__((ext_vector_type(8))) short bf16x8;   // 8 bf16 = 4 VGPR
typedef __attribute__((ext_vector_type(4))) short bf16x4;   // 4 bf16 = 2 VGPR
typedef __attribute__((ext_vector_type(4))) float f32x4;

#define D_MODEL 2048
#define SEQ     2048
#define NH      16
#define HD      128
#define BK      32

__device__ __forceinline__ u16 f2bf(float f){
  union { float f; unsigned u; } v; v.f = f;
  unsigned r = (v.u + 0x7FFFu + ((v.u >> 16) & 1u)) >> 16;  // RNE
  return (u16)r;
}

#if __has_builtin(__builtin_amdgcn_cvt_pk_bf16_f32)
__device__ __forceinline__ unsigned pack2bf(float a, float b){
  auto v = __builtin_amdgcn_cvt_pk_bf16_f32(a, b);
  unsigned u; __builtin_memcpy(&u, &v, 4); return u;
}
#else
__device__ __forceinline__ unsigned pack2bf(float a, float b){
  return (unsigned)f2bf(a) | ((unsigned)f2bf(b) << 16);
}
#endif

__device__ __forceinline__ void gll16(const void* g, void* l){
  __builtin_amdgcn_global_load_lds(
      (const __attribute__((address_space(1))) void*)g,
      (__attribute__((address_space(3))) void*)l, 16, 0, 0);
}

// ---------------- fused prep: fp32->bf16 convert of q,k,v + 4 transposes ----
__global__ __launch_bounds__(256) void prep_kernel(
    const float4* __restrict__ qa, const float4* __restrict__ ka, const float4* __restrict__ va,
    ushort4* __restrict__ oq, ushort4* __restrict__ ok, ushort4* __restrict__ ov,
    const float* __restrict__ Wq, const float* __restrict__ Wo,
    const float* __restrict__ Wk, const float* __restrict__ Wv,
    u16* __restrict__ WqT, u16* __restrict__ WoT,
    u16* __restrict__ WkT, u16* __restrict__ WvT){
  __shared__ float tt[32][33];
  int bid = blockIdx.x;
  if (bid < 8192){
    int i = bid*256 + threadIdx.x;
    float4 a = qa[i], b = ka[i], c = va[i];
    ushort4 ra, rb, rc;
    ra.x=f2bf(a.x); ra.y=f2bf(a.y); ra.z=f2bf(a.z); ra.w=f2bf(a.w);
    rb.x=f2bf(b.x); rb.y=f2bf(b.y); rb.z=f2bf(b.z); rb.w=f2bf(b.w);
    rc.x=f2bf(c.x); rc.y=f2bf(c.y); rc.z=f2bf(c.z); rc.w=f2bf(c.w);
    oq[i]=ra; ok[i]=rb; ov[i]=rc;
    return;
  }
  int id = bid - 8192;
  const float* in; u16* outp; int C, bx, by;
  if (id < 4096)      { in=Wq; outp=WqT; C=2048; bx=id&63;        by=id>>6; }
  else if (id < 8192) { id-=4096; in=Wo; outp=WoT; C=2048; bx=id&63; by=id>>6; }
  else if (id < 8448) { id-=8192; in=Wk; outp=WkT; C=128;  bx=id&3;  by=id>>2; }
  else                { id-=8448; in=Wv; outp=WvT; C=128;  bx=id&3;  by=id>>2; }
  const int R = 2048;
  int c0 = bx*32, r0 = by*32;
  int tx = threadIdx.x & 31, ty = threadIdx.x >> 5;   // (32,8) flattened
  #pragma unroll
  for (int k=0;k<4;k++) tt[ty+k*8][tx] = in[(size_t)(r0+ty+k*8)*C + c0+tx];
  __syncthreads();
  #pragma unroll
  for (int k=0;k<4;k++) outp[(size_t)(c0+ty+k*8)*R + r0+tx] = f2bf(tt[tx][ty+k*8]);
}

// ---------------- depth-3 GEMM core: counted vmcnt + raw barrier ----------
// 3 LDS buffers per operand (8KB each). Tile i+2's glls issued at iter i and
// stay in flight across the barrier (vmcnt(4) = allow the 4 newest per wave).
__device__ __forceinline__ void gemm_core_3p(
    const u16* __restrict__ A, const u16* __restrict__ BT,
    int lda, int ldb, int m0, int n0, int kbeg, int kend,
    u16* As, u16* Bs, f32x4 acc[4][4])
{
  const int t = threadIdx.x;
  const int w = t >> 6, l = t & 63;
  const int wr = w >> 1, wc = w & 1;
  const int c16 = l & 15, q = l >> 4;
  const int srow = l >> 2;
  const int sc   = ((l & 3) ^ ((l >> 3) & 3)) * 8;

  int aoff[4], boff[4];
  #pragma unroll
  for (int mt=0;mt<4;mt++){
    int row = wr*64 + mt*16 + c16;
    aoff[mt] = row*BK + ((q ^ ((row>>1)&3))*8);
  }
  #pragma unroll
  for (int nt=0;nt<4;nt++){
    int row = wc*64 + nt*16 + c16;
    boff[nt] = row*BK + ((q ^ ((row>>1)&3))*8);
  }

  auto issue = [&](int k0, int buf){
    u16* Ad = As + buf*4096;
    u16* Bd = Bs + buf*4096;
    #pragma unroll
    for (int half=0; half<2; half++){
      int r = half*64 + w*16 + srow;
      gll16(A  + (size_t)(m0+r)*lda + k0 + sc, Ad + (half*64 + w*16)*BK);
      gll16(BT + (size_t)(n0+r)*ldb + k0 + sc, Bd + (half*64 + w*16)*BK);
    }
  };

  const int n = (kend - kbeg) / BK;   // >= 16 in all uses
  issue(kbeg, 0);
  issue(kbeg + BK, 1);
  int bi = 0;
  for (int i = 0; i < n; i++){
    // wait tile i arrived (4 oldest glls per wave); keep tile i+1 (and, after
    // issue below, i+2) in flight across the barrier.
    if (i + 1 < n) asm volatile("s_waitcnt vmcnt(4)" ::: "memory");
    else           asm volatile("s_waitcnt vmcnt(0)" ::: "memory");
    __builtin_amdgcn_s_barrier();     // all waves' tile-i glls done; buf
                                      // (i+2)%3's readers (iter i-1) done
    if (i + 2 < n){
      int nb = bi + 2; if (nb >= 3) nb -= 3;
      issue(kbeg + (i+2)*BK, nb);
    }
    const u16* Ab = As + bi*4096;
    const u16* Bb = Bs + bi*4096;
    bf16x8 af[4], bfr[4];
    #pragma unroll
    for (int mt=0;mt<4;mt++) af[mt]  = *(const bf16x8*)(Ab + aoff[mt]);
    #pragma unroll
    for (int nt=0;nt<4;nt++) bfr[nt] = *(const bf16x8*)(Bb + boff[nt]);
    #pragma unroll
    for (int mt=0;mt<4;mt++)
      #pragma unroll
      for (int nt=0;nt<4;nt++)
        acc[mt][nt] = __builtin_amdgcn_mfma_f32_16x16x32_bf16(af[mt], bfr[nt], acc[mt][nt], 0,0,0);
    bi++; if (bi == 3) bi = 0;
  }
}

// ---------------- fused Q-projection + K/V projection ----------------
__global__ __launch_bounds__(256) void proj_kernel(
    const u16* __restrict__ qb, const u16* __restrict__ kb, const u16* __restrict__ vb,
    const u16* __restrict__ WqT, const u16* __restrict__ WkT, const u16* __restrict__ WvT,
    const float* __restrict__ bq, u16* __restrict__ Qp, float* __restrict__ part)
{
  __shared__ u16 As[3*4096], Bs[3*4096];
  f32x4 acc[4][4];
  f32x4 z = {0.f,0.f,0.f,0.f};
  #pragma unroll
  for (int i=0;i<4;i++) for (int j=0;j<4;j++) acc[i][j] = z;
  const int t = threadIdx.x, w = t>>6, l = t&63, wr = w>>1, wc = w&1, c16 = l&15, q = l>>4;
  int id = blockIdx.x;
  if (id < 512){
    int x = id & 7, j = id >> 3;          // bijective XCD-chunk swizzle
    int m0 = (x*4 + (j & 3))*128, n0 = (j >> 2)*128;
    gemm_core_3p(qb, WqT, 2048, 2048, m0, n0, 0, 2048, As, Bs, acc);
    #pragma unroll
    for (int mt=0;mt<4;mt++)
      #pragma unroll
      for (int nt=0;nt<4;nt++){
        int col = n0 + wc*64 + nt*16 + c16;
        float bv = bq[col];
        #pragma unroll
        for (int r=0;r<4;r++){
          int row = m0 + wr*64 + mt*16 + q*4 + r;
          Qp[(size_t)row*D_MODEL + col] = f2bf(acc[mt][nt][r] + bv);
        }
      }
  } else {
    int kvid = id - 512;
    int zi = kvid & 3, nb = (kvid >> 2) & 1, mi = kvid >> 3;
    const u16* Am = nb ? vb  : kb;
    const u16* Bm = nb ? WvT : WkT;
    gemm_core_3p(Am, Bm, 2048, 2048, mi*128, 0, zi*512, zi*512+512, As, Bs, acc);
    float* dst = part + (size_t)(zi*2 + nb)*524288;   // [z][nb][4096][128]
    #pragma unroll
    for (int mt=0;mt<4;mt++)
      #pragma unroll
      for (int nt=0;nt<4;nt++){
        int col = wc*64 + nt*16 + c16;
        #pragma unroll
        for (int r=0;r<4;r++){
          int row = mi*128 + wr*64 + mt*16 + q*4 + r;
          dst[(size_t)row*128 + col] = acc[mt][nt][r];
        }
      }
  }
}

// ---------------- O-projection GEMM + bias, fp32 out (XCD-chunk swizzle) ----
__global__ __launch_bounds__(256) void oproj_kernel(
    const u16* __restrict__ A, const u16* __restrict__ BT, const float* __restrict__ bias,
    float* __restrict__ C)
{
  __shared__ u16 As[3*4096], Bs[3*4096];
  f32x4 acc[4][4];
  f32x4 z = {0.f,0.f,0.f,0.f};
  #pragma unroll
  for (int i=0;i<4;i++) for (int j=0;j<4;j++) acc[i][j] = z;
  int id = blockIdx.x;
  int x = id & 7, j = id >> 3;            // bijective XCD-chunk swizzle
  int m0 = (x*4 + (j & 3))*128, n0 = (j >> 2)*128;
  gemm_core_3p(A, BT, 2048, 2048, m0, n0, 0, 2048, As, Bs, acc);
  const int t = threadIdx.x, w = t>>6, l = t&63, wr = w>>1, wc = w&1, c16 = l&15, q = l>>4;
  #pragma unroll
  for (int mt=0;mt<4;mt++)
    #pragma unroll
    for (int nt=0;nt<4;nt++){
      int col = n0 + wc*64 + nt*16 + c16;
      float bv = bias[col];
      #pragma unroll
      for (int r=0;r<4;r++){
        int row = m0 + wr*64 + mt*16 + q*4 + r;
        C[(size_t)row*D_MODEL + col] = acc[mt][nt][r] + bv;
      }
    }
}

// ---------------- reduce split-K partials; Kp bf16 [4096][128], VpT bf16 [B][128][S] ----------------
__global__ __launch_bounds__(256) void kv_reduce_kernel(
    const float* __restrict__ part, const float* __restrict__ bk, const float* __restrict__ bv,
    u16* __restrict__ Kp, u16* __restrict__ VpT){
  int idx = blockIdx.x*256 + threadIdx.x;
  int d = idx & 127, sg = idx >> 7;
  float ka = 0.f, va = 0.f;
  #pragma unroll
  for (int zi=0; zi<4; zi++){
    ka += part[(size_t)(zi*2+0)*524288 + idx];
    va += part[(size_t)(zi*2+1)*524288 + idx];
  }
  Kp[idx] = f2bf(ka + bk[d]);
  int b = sg >> 11, sl = sg & 2047;
  VpT[(size_t)b*262144 + (size_t)d*2048 + sl] = f2bf(va + bv[d]);
}

// ---------------- flash attention (v11, unchanged) ----------
// 8 waves x 32 q-rows (2 q-sets); grid (8,32) = 256 blocks = 1/CU.
// K+V double-buffered (128 KB), 1 barrier/kt, merged K=32 PV, defer-max.
__global__ __launch_bounds__(512, 2) void attn_kernel(
    const u16* __restrict__ Qp, const u16* __restrict__ Kp,
    const u16* __restrict__ VpT, u16* __restrict__ attnb){
  __shared__ u16 lds[65536];    // 128 KB
  const int t = threadIdx.x;
  const int w = t >> 6, l = t & 63;
  const int c16 = l & 15, q = l >> 4;

  const int qt = blockIdx.x;           // 0..7
  const int bh = blockIdx.y;           // 0..31
  const int b = bh >> 4, h = bh & 15;

  const u16* Qbase = Qp  + ((size_t)(b*SEQ + qt*256 + w*32))*D_MODEL + h*HD;
  const u16* Kbase = Kp  + (size_t)(b*SEQ)*HD;
  const u16* Vbase = VpT + (size_t)b*HD*SEQ;

  const int sr = w*4 + (l >> 4);       // staging row within 32-row group
  // ---- prologue: issue K0+V0 glls; Q frags global->reg ----
  #pragma unroll
  for (int j=0;j<4;j++){
    int r = j*32 + sr;
    int g = (l & 15) ^ (r & 15);
    gll16(Kbase + (size_t)r*HD + g*8, lds + j*4096 + w*512);
  }
  #pragma unroll
  for (int j=0;j<4;j++){
    int d = j*32 + sr;
    int g = (l & 15) ^ (d & 15);
    gll16(Vbase + (size_t)d*SEQ + g*8, lds + 32768 + j*4096 + w*512);
  }
  bf16x8 qf[2][4];
  #pragma unroll
  for (int qs=0;qs<2;qs++)
    #pragma unroll
    for (int kk=0;kk<4;kk++)
      qf[qs][kk] = *(const bf16x8*)(Qbase + (size_t)(qs*16 + c16)*D_MODEL + (kk*4 + q)*8);
  __syncthreads();   // K0+V0 arrived

  f32x4 o[2][8];
  f32x4 z4 = {0.f,0.f,0.f,0.f};
  #pragma unroll
  for (int qs=0;qs<2;qs++) for (int dt=0;dt<8;dt++) o[qs][dt] = z4;
  float mrow[2] = {-1e30f, -1e30f};
  float lrow[2] = {0.f, 0.f};
  const float cs = 0.08838834764831845f * 1.4426950408889634f;  // (1/sqrt(128))*log2(e)

  for (int kt = 0; kt < 16; kt++){
    const int p = kt & 1;
    // issue ALL glls for tile kt+1 into the idle buffer (p^1)
    if (kt < 15){
      u16* Kd = lds + (p^1)*16384;
      u16* Vd = lds + 32768 + (p^1)*16384;
      #pragma unroll
      for (int j=0;j<4;j++){
        int r = j*32 + sr;
        int g = (l & 15) ^ (r & 15);
        gll16(Kbase + (size_t)((kt+1)*128 + r)*HD + g*8, Kd + j*4096 + w*512);
      }
      #pragma unroll
      for (int j=0;j<4;j++){
        int d = j*32 + sr;
        int g = (l & 15) ^ (d & 15);
        gll16(Vbase + (size_t)d*SEQ + (kt+1)*128 + g*8, Vd + j*4096 + w*512);
      }
    }
    const u16* Ks = lds + p*16384;
    const u16* Vs = lds + 32768 + p*16384;

    // S^T = K Q^T : each kf LDS read feeds both q-sets; kk==0 uses C=z4
    f32x4 s[2][8];
    __builtin_amdgcn_s_setprio(1);
    #pragma unroll
    for (int kt8=0; kt8<8; kt8++){
      {
        bf16x8 kf = *(const bf16x8*)(Ks + (kt8*16 + c16)*128 + ((q ^ c16) & 15)*8);
        s[0][kt8] = __builtin_amdgcn_mfma_f32_16x16x32_bf16(kf, qf[0][0], z4, 0,0,0);
        s[1][kt8] = __builtin_amdgcn_mfma_f32_16x16x32_bf16(kf, qf[1][0], z4, 0,0,0);
      }
      #pragma unroll
      for (int kk=1;kk<4;kk++){
        int ch = kk*4 + q;
        bf16x8 kf = *(const bf16x8*)(Ks + (kt8*16 + c16)*128 + ((ch ^ c16) & 15)*8);
        s[0][kt8] = __builtin_amdgcn_mfma_f32_16x16x32_bf16(kf, qf[0][kk], s[0][kt8], 0,0,0);
        s[1][kt8] = __builtin_amdgcn_mfma_f32_16x16x32_bf16(kf, qf[1][kk], s[1][kt8], 0,0,0);
      }
    }
    __builtin_amdgcn_s_setprio(0);

    // online softmax with defer-max (slack 8 exponent units)
    float vmax[2];
    #pragma unroll
    for (int qs=0; qs<2; qs++){
      float xx[8];
      #pragma unroll
      for (int kt8=0;kt8<8;kt8++)
        xx[kt8] = fmaxf(fmaxf(s[qs][kt8][0],s[qs][kt8][1]), fmaxf(s[qs][kt8][2],s[qs][kt8][3]));
      float vm = fmaxf(fmaxf(fmaxf(xx[0],xx[1]),fmaxf(xx[2],xx[3])),
                       fmaxf(fmaxf(xx[4],xx[5]),fmaxf(xx[6],xx[7])));
      vm = fmaxf(vm, __shfl_xor(vm, 16));
      vm = fmaxf(vm, __shfl_xor(vm, 32));
      vmax[qs] = vm;
    }
    bool upd = ((vmax[0]-mrow[0])*cs > 8.f) || ((vmax[1]-mrow[1])*cs > 8.f);
    if (__any(upd)){                      // rare after tile 0
      #pragma unroll
      for (int qs=0; qs<2; qs++){
        float mnew = fmaxf(mrow[qs], vmax[qs]);
        float a = exp2f((mrow[qs]-mnew)*cs);
        mrow[qs] = mnew; lrow[qs] *= a;
        #pragma unroll
        for (int dt=0;dt<8;dt++)
          #pragma unroll
          for (int r=0;r<4;r++) o[qs][dt][r] *= a;
      }
    }
    union PU { unsigned u[4]; bf16x8 v; } P32[2][4];
    #pragma unroll
    for (int qs=0; qs<2; qs++){
      float mc = mrow[qs]*cs;
      float rsum = 0.f;
      #pragma unroll
      for (int kt8=0;kt8<8;kt8++){
        float p0 = exp2f(__builtin_fmaf(s[qs][kt8][0], cs, -mc));
        float p1 = exp2f(__builtin_fmaf(s[qs][kt8][1], cs, -mc));
        float p2 = exp2f(__builtin_fmaf(s[qs][kt8][2], cs, -mc));
        float p3 = exp2f(__builtin_fmaf(s[qs][kt8][3], cs, -mc));
        s[qs][kt8][0]=p0; s[qs][kt8][1]=p1; s[qs][kt8][2]=p2; s[qs][kt8][3]=p3;
        rsum += (p0+p1)+(p2+p3);
      }
      rsum += __shfl_xor(rsum, 16);
      rsum += __shfl_xor(rsum, 32);
      lrow[qs] += rsum;
      // P32[qs][kb]: slots 0..3 = keys 32kb+4q+r, slots 4..7 = keys 32kb+16+4q+r
      #pragma unroll
      for (int kb=0;kb<4;kb++){
        P32[qs][kb].u[0] = pack2bf(s[qs][2*kb][0],   s[qs][2*kb][1]);
        P32[qs][kb].u[1] = pack2bf(s[qs][2*kb][2],   s[qs][2*kb][3]);
        P32[qs][kb].u[2] = pack2bf(s[qs][2*kb+1][0], s[qs][2*kb+1][1]);
        P32[qs][kb].u[3] = pack2bf(s[qs][2*kb+1][2], s[qs][2*kb+1][3]);
      }
    }

    // O^T += V^T P^T : each vf LDS read feeds both q-sets
    __builtin_amdgcn_s_setprio(1);
    #pragma unroll
    for (int kb=0; kb<4; kb++){
      int ca = 4*kb + (q>>1);       // chunk for k=32kb+4q (half q&1)
      int cb = ca + 2;              // chunk for k=32kb+16+4q
      #pragma unroll
      for (int dt=0; dt<8; dt++){
        int d = dt*16 + c16;
        union VU { bf16x4 hh[2]; bf16x8 v; } vf;
        vf.hh[0] = *(const bf16x4*)(Vs + d*128 + ((ca ^ c16) & 15)*8 + (q&1)*4);
        vf.hh[1] = *(const bf16x4*)(Vs + d*128 + ((cb ^ c16) & 15)*8 + (q&1)*4);
        o[0][dt] = __builtin_amdgcn_mfma_f32_16x16x32_bf16(vf.v, P32[0][kb].v, o[0][dt], 0,0,0);
        o[1][dt] = __builtin_amdgcn_mfma_f32_16x16x32_bf16(vf.v, P32[1][kb].v, o[1][dt], 0,0,0);
      }
    }
    __builtin_amdgcn_s_setprio(0);
    __syncthreads();   // drains tile kt+1 glls; certifies buf p readers done
  }

  // normalize + write: lane holds O[q=c16+16qs][d=dt*16+quad*4+r]
  #pragma unroll
  for (int qs=0;qs<2;qs++){
    float inv = 1.f / lrow[qs];
    int qrow = qt*256 + w*32 + qs*16 + c16;
    u16* dst = attnb + ((size_t)(b*SEQ) + qrow)*D_MODEL + h*HD + q*4;
    #pragma unroll
    for (int dt=0;dt<8;dt++){
      ushort4 pk;
      pk.x = f2bf(o[qs][dt][0]*inv);
      pk.y = f2bf(o[qs][dt][1]*inv);
      pk.z = f2bf(o[qs][dt][2]*inv);
      pk.w = f2bf(o[qs][dt][3]*inv);
      *(ushort4*)(dst + dt*16) = pk;
    }
  }
}

extern "C" void kernel_launch(void* const* d_in, const int* in_sizes, int n_in,
                              void* d_out, int out_size, void* d_ws, size_t ws_size,
                              hipStream_t stream) {
  (void)in_sizes; (void)n_in; (void)out_size; (void)ws_size;
  const float* query = (const float*)d_in[0];
  const float* key   = (const float*)d_in[1];
  const float* value = (const float*)d_in[2];
  const float* Wq    = (const float*)d_in[3];
  const float* bq    = (const float*)d_in[4];
  const float* Wk    = (const float*)d_in[5];
  const float* bk    = (const float*)d_in[6];
  const float* Wv    = (const float*)d_in[7];
  const float* bv    = (const float*)d_in[8];
  const float* Wo    = (const float*)d_in[9];
  const float* bo    = (const float*)d_in[10];
  float* out = (float*)d_out;

  char* W = (char*)d_ws;
  u16*  qb     = (u16*) (W + 0);          // 16 MB  bf16 query [4096][2048]
  u16*  kb     = (u16*) (W + 16777216);   // 16 MB  bf16 key
  u16*  vb     = (u16*) (W + 33554432);   // 16 MB  bf16 value
  u16*  WqT    = (u16*) (W + 50331648);   //  8 MB  Wq^T  [2048][2048]
  u16*  WoT    = (u16*) (W + 58720256);   //  8 MB  Wo^T
  u16*  WkT    = (u16*) (W + 67108864);   // .5 MB  Wk^T  [128][2048]
  u16*  WvT    = (u16*) (W + 67633152);   // .5 MB  Wv^T
  u16*  Qp     = (u16*) (W + 68157440);   // 16 MB  Q proj bf16 [4096][2048]
  u16*  Kp     = (u16*) (W + 84934656);   //  1 MB  K proj bf16 [4096][128]
  u16*  VpT    = (u16*) (W + 85983232);   //  1 MB  V proj^T bf16 [B][128][2048]
  u16*  attnb  = (u16*) (W + 87031808);   // 16 MB  attention out bf16 [4096][2048]
  float* kvpart= (float*)(W + 103809024); // 16 MB  split-K partials [4][2][4096][128]

  prep_kernel<<<16896, 256, 0, stream>>>(
      (const float4*)query, (const float4*)key, (const float4*)value,
      (ushort4*)qb, (ushort4*)kb, (ushort4*)vb,
      Wq, Wo, Wk, Wv, WqT, WoT, WkT, WvT);
  proj_kernel<<<768, 256, 0, stream>>>(qb, kb, vb, WqT, WkT, WvT, bq, Qp, kvpart);
  kv_reduce_kernel<<<2048, 256, 0, stream>>>(kvpart, bk, bv, Kp, VpT);
  attn_kernel<<<dim3(8,32), 512, 0, stream>>>(Qp, Kp, VpT, attnb);
  oproj_kernel<<<512, 256, 0, stream>>>(attnb, WoT, bo, out);
}

// Round 10
// 385.716 us; speedup vs baseline: 1.0708x; 1.0482x over previous
//
#include <hip/hip_runtime.h>

// MQA: B=2, S=2048, D=2048, H=16, HD=128.  GEMMs bf16 MFMA 16x16x32, fp32 acc.
// v13: Q-PROJECTION FUSED INTO ATTN. Each attn block computes its own Q-tile
// (256 rows x 128 head-cols, K=2048) in a phase-0 mini-GEMM accumulating into
// the (zero) o[2][8] registers, bias+packs it to an LDS Q-tile (chunk-XOR
// swizzle, both-sides), reads qf frags, re-zeros o, then runs the v11 main
// loop unchanged. proj_kernel shrinks to KV-only (256 blocks). Rationale:
// attn idles ~44% of issue slots (MfmaUtil 25) while proj-Q burns ~100us at
// ~330 TF; fusion absorbs 8192 MFMAs/block (~17us/CU floor) into the bubbles
// and deletes the 32MB Qp round-trip. v12 depth-3 staging reused (null alone
// but proven-correct; phase-0 uses it with 3 glls/iter, vmcnt(3)).

typedef unsigned short u16;
typedef __attribute__((ext_vector_type(8))) short bf16x8;   // 8 bf16 = 4 VGPR
typedef __attribute__((ext_vector_type(4))) short bf16x4;   // 4 bf16 = 2 VGPR
typedef __attribute__((ext_vector_type(4))) float f32x4;

#define D_MODEL 2048
#define SEQ     2048
#define NH      16
#define HD      128
#define BK      32

__device__ __forceinline__ u16 f2bf(float f){
  union { float f; unsigned u; } v; v.f = f;
  unsigned r = (v.u + 0x7FFFu + ((v.u >> 16) & 1u)) >> 16;  // RNE
  return (u16)r;
}

#if __has_builtin(__builtin_amdgcn_cvt_pk_bf16_f32)
__device__ __forceinline__ unsigned pack2bf(float a, float b){
  auto v = __builtin_amdgcn_cvt_pk_bf16_f32(a, b);
  unsigned u; __builtin_memcpy(&u, &v, 4); return u;
}
#else
__device__ __forceinline__ unsigned pack2bf(float a, float b){
  return (unsigned)f2bf(a) | ((unsigned)f2bf(b) << 16);
}
#endif

__device__ __forceinline__ void gll16(const void* g, void* l){
  __builtin_amdgcn_global_load_lds(
      (const __attribute__((address_space(1))) void*)g,
      (__attribute__((address_space(3))) void*)l, 16, 0, 0);
}

// ---------------- fused prep: fp32->bf16 convert of q,k,v + 4 transposes ----
__global__ __launch_bounds__(256) void prep_kernel(
    const float4* __restrict__ qa, const float4* __restrict__ ka, const float4* __restrict__ va,
    ushort4* __restrict__ oq, ushort4* __restrict__ ok, ushort4* __restrict__ ov,
    const float* __restrict__ Wq, const float* __restrict__ Wo,
    const float* __restrict__ Wk, const float* __restrict__ Wv,
    u16* __restrict__ WqT, u16* __restrict__ WoT,
    u16* __restrict__ WkT, u16* __restrict__ WvT){
  __shared__ float tt[32][33];
  int bid = blockIdx.x;
  if (bid < 8192){
    int i = bid*256 + threadIdx.x;
    float4 a = qa[i], b = ka[i], c = va[i];
    ushort4 ra, rb, rc;
    ra.x=f2bf(a.x); ra.y=f2bf(a.y); ra.z=f2bf(a.z); ra.w=f2bf(a.w);
    rb.x=f2bf(b.x); rb.y=f2bf(b.y); rb.z=f2bf(b.z); rb.w=f2bf(b.w);
    rc.x=f2bf(c.x); rc.y=f2bf(c.y); rc.z=f2bf(c.z); rc.w=f2bf(c.w);
    oq[i]=ra; ok[i]=rb; ov[i]=rc;
    return;
  }
  int id = bid - 8192;
  const float* in; u16* outp; int C, bx, by;
  if (id < 4096)      { in=Wq; outp=WqT; C=2048; bx=id&63;        by=id>>6; }
  else if (id < 8192) { id-=4096; in=Wo; outp=WoT; C=2048; bx=id&63; by=id>>6; }
  else if (id < 8448) { id-=8192; in=Wk; outp=WkT; C=128;  bx=id&3;  by=id>>2; }
  else                { id-=8448; in=Wv; outp=WvT; C=128;  bx=id&3;  by=id>>2; }
  const int R = 2048;
  int c0 = bx*32, r0 = by*32;
  int tx = threadIdx.x & 31, ty = threadIdx.x >> 5;   // (32,8) flattened
  #pragma unroll
  for (int k=0;k<4;k++) tt[ty+k*8][tx] = in[(size_t)(r0+ty+k*8)*C + c0+tx];
  __syncthreads();
  #pragma unroll
  for (int k=0;k<4;k++) outp[(size_t)(c0+ty+k*8)*R + r0+tx] = f2bf(tt[tx][ty+k*8]);
}

// ---------------- depth-3 GEMM core: counted vmcnt + raw barrier ----------
__device__ __forceinline__ void gemm_core_3p(
    const u16* __restrict__ A, const u16* __restrict__ BT,
    int lda, int ldb, int m0, int n0, int kbeg, int kend,
    u16* As, u16* Bs, f32x4 acc[4][4])
{
  const int t = threadIdx.x;
  const int w = t >> 6, l = t & 63;
  const int wr = w >> 1, wc = w & 1;
  const int c16 = l & 15, q = l >> 4;
  const int srow = l >> 2;
  const int sc   = ((l & 3) ^ ((l >> 3) & 3)) * 8;

  int aoff[4], boff[4];
  #pragma unroll
  for (int mt=0;mt<4;mt++){
    int row = wr*64 + mt*16 + c16;
    aoff[mt] = row*BK + ((q ^ ((row>>1)&3))*8);
  }
  #pragma unroll
  for (int nt=0;nt<4;nt++){
    int row = wc*64 + nt*16 + c16;
    boff[nt] = row*BK + ((q ^ ((row>>1)&3))*8);
  }

  auto issue = [&](int k0, int buf){
    u16* Ad = As + buf*4096;
    u16* Bd = Bs + buf*4096;
    #pragma unroll
    for (int half=0; half<2; half++){
      int r = half*64 + w*16 + srow;
      gll16(A  + (size_t)(m0+r)*lda + k0 + sc, Ad + (half*64 + w*16)*BK);
      gll16(BT + (size_t)(n0+r)*ldb + k0 + sc, Bd + (half*64 + w*16)*BK);
    }
  };

  const int n = (kend - kbeg) / BK;
  issue(kbeg, 0);
  issue(kbeg + BK, 1);
  int bi = 0;
  for (int i = 0; i < n; i++){
    if (i + 1 < n) asm volatile("s_waitcnt vmcnt(4)" ::: "memory");
    else           asm volatile("s_waitcnt vmcnt(0)" ::: "memory");
    __builtin_amdgcn_s_barrier();
    if (i + 2 < n){
      int nb = bi + 2; if (nb >= 3) nb -= 3;
      issue(kbeg + (i+2)*BK, nb);
    }
    const u16* Ab = As + bi*4096;
    const u16* Bb = Bs + bi*4096;
    bf16x8 af[4], bfr[4];
    #pragma unroll
    for (int mt=0;mt<4;mt++) af[mt]  = *(const bf16x8*)(Ab + aoff[mt]);
    #pragma unroll
    for (int nt=0;nt<4;nt++) bfr[nt] = *(const bf16x8*)(Bb + boff[nt]);
    #pragma unroll
    for (int mt=0;mt<4;mt++)
      #pragma unroll
      for (int nt=0;nt<4;nt++)
        acc[mt][nt] = __builtin_amdgcn_mfma_f32_16x16x32_bf16(af[mt], bfr[nt], acc[mt][nt], 0,0,0);
    bi++; if (bi == 3) bi = 0;
  }
}

// ---------------- K/V projection only (split-K=4, fp32 partials) ----------
__global__ __launch_bounds__(256) void proj_kernel(
    const u16* __restrict__ kb, const u16* __restrict__ vb,
    const u16* __restrict__ WkT, const u16* __restrict__ WvT,
    float* __restrict__ part)
{
  __shared__ u16 As[3*4096], Bs[3*4096];
  f32x4 acc[4][4];
  f32x4 z = {0.f,0.f,0.f,0.f};
  #pragma unroll
  for (int i=0;i<4;i++) for (int j=0;j<4;j++) acc[i][j] = z;
  const int t = threadIdx.x, w = t>>6, l = t&63, wr = w>>1, wc = w&1, c16 = l&15, q = l>>4;
  int id = blockIdx.x;                    // 0..255
  int zi = id & 3, nb = (id >> 2) & 1, mi = id >> 3;
  const u16* Am = nb ? vb  : kb;
  const u16* Bm = nb ? WvT : WkT;
  gemm_core_3p(Am, Bm, 2048, 2048, mi*128, 0, zi*512, zi*512+512, As, Bs, acc);
  float* dst = part + (size_t)(zi*2 + nb)*524288;   // [z][nb][4096][128]
  #pragma unroll
  for (int mt=0;mt<4;mt++)
    #pragma unroll
    for (int nt=0;nt<4;nt++){
      int col = wc*64 + nt*16 + c16;
      #pragma unroll
      for (int r=0;r<4;r++){
        int row = mi*128 + wr*64 + mt*16 + q*4 + r;
        dst[(size_t)row*128 + col] = acc[mt][nt][r];
      }
    }
}

// ---------------- O-projection GEMM + bias, fp32 out (XCD-chunk swizzle) ----
__global__ __launch_bounds__(256) void oproj_kernel(
    const u16* __restrict__ A, const u16* __restrict__ BT, const float* __restrict__ bias,
    float* __restrict__ C)
{
  __shared__ u16 As[3*4096], Bs[3*4096];
  f32x4 acc[4][4];
  f32x4 z = {0.f,0.f,0.f,0.f};
  #pragma unroll
  for (int i=0;i<4;i++) for (int j=0;j<4;j++) acc[i][j] = z;
  int id = blockIdx.x;
  int x = id & 7, j = id >> 3;            // bijective XCD-chunk swizzle
  int m0 = (x*4 + (j & 3))*128, n0 = (j >> 2)*128;
  gemm_core_3p(A, BT, 2048, 2048, m0, n0, 0, 2048, As, Bs, acc);
  const int t = threadIdx.x, w = t>>6, l = t&63, wr = w>>1, wc = w&1, c16 = l&15, q = l>>4;
  #pragma unroll
  for (int mt=0;mt<4;mt++)
    #pragma unroll
    for (int nt=0;nt<4;nt++){
      int col = n0 + wc*64 + nt*16 + c16;
      float bv = bias[col];
      #pragma unroll
      for (int r=0;r<4;r++){
        int row = m0 + wr*64 + mt*16 + q*4 + r;
        C[(size_t)row*D_MODEL + col] = acc[mt][nt][r] + bv;
      }
    }
}

// ---------------- reduce split-K partials ----------------
__global__ __launch_bounds__(256) void kv_reduce_kernel(
    const float* __restrict__ part, const float* __restrict__ bk, const float* __restrict__ bv,
    u16* __restrict__ Kp, u16* __restrict__ VpT){
  int idx = blockIdx.x*256 + threadIdx.x;
  int d = idx & 127, sg = idx >> 7;
  float ka = 0.f, va = 0.f;
  #pragma unroll
  for (int zi=0; zi<4; zi++){
    ka += part[(size_t)(zi*2+0)*524288 + idx];
    va += part[(size_t)(zi*2+1)*524288 + idx];
  }
  Kp[idx] = f2bf(ka + bk[d]);
  int b = sg >> 11, sl = sg & 2047;
  VpT[(size_t)b*262144 + (size_t)d*2048 + sl] = f2bf(va + bv[d]);
}

// ---------------- flash attention v13: fused Q-proj + v11 main loop --------
// Phase 0: Q-tile = qb[R0..R0+256] @ WqT[h*128..+128]^T (K=2048, 64 iters,
// depth-3 staging, acc in o[2][8]); bias+pack -> LDS Qt (chunk-XOR swizzle);
// qf read; re-zero o. Then v11: K+V dbuf, 1 barrier/kt, merged K=32 PV,
// defer-max slack 8.
__global__ __launch_bounds__(512, 2) void attn_kernel(
    const u16* __restrict__ qb, const u16* __restrict__ WqT, const float* __restrict__ bq,
    const u16* __restrict__ Kp, const u16* __restrict__ VpT, u16* __restrict__ attnb){
  __shared__ u16 lds[65536];    // 128 KB
  const int t = threadIdx.x;
  const int w = t >> 6, l = t & 63;
  const int c16 = l & 15, q = l >> 4;

  const int qt = blockIdx.x;           // 0..7
  const int bh = blockIdx.y;           // 0..31
  const int b = bh >> 4, h = bh & 15;

  f32x4 o[2][8];
  f32x4 z4 = {0.f,0.f,0.f,0.f};
  #pragma unroll
  for (int qs=0;qs<2;qs++) for (int dt=0;dt<8;dt++) o[qs][dt] = z4;

  // ================= Phase 0: fused Q-projection =================
  {
    const u16* Aq = qb  + (size_t)(b*SEQ + qt*256)*D_MODEL;  // 256 q-rows
    const u16* Bw = WqT + (size_t)(h*HD)*D_MODEL;            // 128 out-cols
    u16* As = lds;            // 3 x 8192 u16 (16 KB each)
    u16* Bs = lds + 24576;    // 3 x 4096 u16 ( 8 KB each)
    const int srow = l >> 2;
    const int sc   = ((l & 3) ^ ((l >> 3) & 3)) * 8;
    auto issueQ = [&](int k0, int buf){
      u16* Ad = As + buf*8192;
      u16* Bd = Bs + buf*4096;
      #pragma unroll
      for (int half=0; half<2; half++){
        int r = half*128 + w*16 + srow;
        gll16(Aq + (size_t)r*D_MODEL + k0 + sc, Ad + (half*128 + w*16)*BK);
      }
      { int r = w*16 + srow;
        gll16(Bw + (size_t)r*D_MODEL + k0 + sc, Bd + (w*16)*BK); }
    };
    issueQ(0, 0);
    issueQ(BK, 1);
    int bi = 0;
    const int swz = (q ^ ((c16>>1)&3))*8;
    for (int i = 0; i < 64; i++){
      if (i + 1 < 64) asm volatile("s_waitcnt vmcnt(3)" ::: "memory");
      else            asm volatile("s_waitcnt vmcnt(0)" ::: "memory");
      __builtin_amdgcn_s_barrier();
      if (i + 2 < 64){
        int nb2 = bi + 2; if (nb2 >= 3) nb2 -= 3;
        issueQ((i+2)*BK, nb2);
      }
      const u16* Ab = As + bi*8192;
      const u16* Bb = Bs + bi*4096;
      bf16x8 qrow0 = *(const bf16x8*)(Ab + (w*32      + c16)*BK + swz);
      bf16x8 qrow1 = *(const bf16x8*)(Ab + (w*32 + 16 + c16)*BK + swz);
      bf16x8 wcol[8];
      #pragma unroll
      for (int dt=0;dt<8;dt++)
        wcol[dt] = *(const bf16x8*)(Bb + (dt*16 + c16)*BK + swz);
      __builtin_amdgcn_s_setprio(1);
      #pragma unroll
      for (int dt=0;dt<8;dt++){
        o[0][dt] = __builtin_amdgcn_mfma_f32_16x16x32_bf16(wcol[dt], qrow0, o[0][dt], 0,0,0);
        o[1][dt] = __builtin_amdgcn_mfma_f32_16x16x32_bf16(wcol[dt], qrow1, o[1][dt], 0,0,0);
      }
      __builtin_amdgcn_s_setprio(0);
      bi++; if (bi == 3) bi = 0;
    }
    __syncthreads();            // all frag reads done; lds free for Qt
    // bias + pack + write Qt[256][128] (chunk16 XOR swizzle, write side)
    #pragma unroll
    for (int qs=0;qs<2;qs++){
      int row = w*32 + qs*16 + c16;
      #pragma unroll
      for (int dt=0;dt<8;dt++){
        float4 bb = *(const float4*)(bq + h*HD + dt*16 + q*4);
        uint2 val;
        val.x = pack2bf(o[qs][dt][0]+bb.x, o[qs][dt][1]+bb.y);
        val.y = pack2bf(o[qs][dt][2]+bb.z, o[qs][dt][3]+bb.w);
        int ch = dt*2 + (q>>1);
        *(uint2*)(lds + row*128 + ((ch ^ c16)&15)*8 + (q&1)*4) = val;
      }
    }
    __syncthreads();            // Qt complete
  }

  bf16x8 qf[2][4];
  #pragma unroll
  for (int qs=0;qs<2;qs++)
    #pragma unroll
    for (int kk=0;kk<4;kk++){
      int ch = kk*4 + q;
      qf[qs][kk] = *(const bf16x8*)(lds + (w*32 + qs*16 + c16)*128 + ((ch ^ c16)&15)*8);
    }
  __syncthreads();              // all Qt reads done; lds free for K/V
  #pragma unroll
  for (int qs=0;qs<2;qs++) for (int dt=0;dt<8;dt++) o[qs][dt] = z4;

  // ================= v11 main loop =================
  const u16* Kbase = Kp  + (size_t)(b*SEQ)*HD;
  const u16* Vbase = VpT + (size_t)b*HD*SEQ;
  const int sr = w*4 + (l >> 4);
  #pragma unroll
  for (int j=0;j<4;j++){
    int r = j*32 + sr;
    int g = (l & 15) ^ (r & 15);
    gll16(Kbase + (size_t)r*HD + g*8, lds + j*4096 + w*512);
  }
  #pragma unroll
  for (int j=0;j<4;j++){
    int d = j*32 + sr;
    int g = (l & 15) ^ (d & 15);
    gll16(Vbase + (size_t)d*SEQ + g*8, lds + 32768 + j*4096 + w*512);
  }
  __syncthreads();   // K0+V0 arrived

  float mrow[2] = {-1e30f, -1e30f};
  float lrow[2] = {0.f, 0.f};
  const float cs = 0.08838834764831845f * 1.4426950408889634f;  // (1/sqrt(128))*log2(e)

  for (int kt = 0; kt < 16; kt++){
    const int p = kt & 1;
    if (kt < 15){
      u16* Kd = lds + (p^1)*16384;
      u16* Vd = lds + 32768 + (p^1)*16384;
      #pragma unroll
      for (int j=0;j<4;j++){
        int r = j*32 + sr;
        int g = (l & 15) ^ (r & 15);
        gll16(Kbase + (size_t)((kt+1)*128 + r)*HD + g*8, Kd + j*4096 + w*512);
      }
      #pragma unroll
      for (int j=0;j<4;j++){
        int d = j*32 + sr;
        int g = (l & 15) ^ (d & 15);
        gll16(Vbase + (size_t)d*SEQ + (kt+1)*128 + g*8, Vd + j*4096 + w*512);
      }
    }
    const u16* Ks = lds + p*16384;
    const u16* Vs = lds + 32768 + p*16384;

    // S^T = K Q^T : each kf LDS read feeds both q-sets; kk==0 uses C=z4
    f32x4 s[2][8];
    __builtin_amdgcn_s_setprio(1);
    #pragma unroll
    for (int kt8=0; kt8<8; kt8++){
      {
        bf16x8 kf = *(const bf16x8*)(Ks + (kt8*16 + c16)*128 + ((q ^ c16) & 15)*8);
        s[0][kt8] = __builtin_amdgcn_mfma_f32_16x16x32_bf16(kf, qf[0][0], z4, 0,0,0);
        s[1][kt8] = __builtin_amdgcn_mfma_f32_16x16x32_bf16(kf, qf[1][0], z4, 0,0,0);
      }
      #pragma unroll
      for (int kk=1;kk<4;kk++){
        int ch = kk*4 + q;
        bf16x8 kf = *(const bf16x8*)(Ks + (kt8*16 + c16)*128 + ((ch ^ c16) & 15)*8);
        s[0][kt8] = __builtin_amdgcn_mfma_f32_16x16x32_bf16(kf, qf[0][kk], s[0][kt8], 0,0,0);
        s[1][kt8] = __builtin_amdgcn_mfma_f32_16x16x32_bf16(kf, qf[1][kk], s[1][kt8], 0,0,0);
      }
    }
    __builtin_amdgcn_s_setprio(0);

    // online softmax with defer-max (slack 8 exponent units)
    float vmax[2];
    #pragma unroll
    for (int qs=0; qs<2; qs++){
      float xx[8];
      #pragma unroll
      for (int kt8=0;kt8<8;kt8++)
        xx[kt8] = fmaxf(fmaxf(s[qs][kt8][0],s[qs][kt8][1]), fmaxf(s[qs][kt8][2],s[qs][kt8][3]));
      float vm = fmaxf(fmaxf(fmaxf(xx[0],xx[1]),fmaxf(xx[2],xx[3])),
                       fmaxf(fmaxf(xx[4],xx[5]),fmaxf(xx[6],xx[7])));
      vm = fmaxf(vm, __shfl_xor(vm, 16));
      vm = fmaxf(vm, __shfl_xor(vm, 32));
      vmax[qs] = vm;
    }
    bool upd = ((vmax[0]-mrow[0])*cs > 8.f) || ((vmax[1]-mrow[1])*cs > 8.f);
    if (__any(upd)){                      // rare after tile 0
      #pragma unroll
      for (int qs=0; qs<2; qs++){
        float mnew = fmaxf(mrow[qs], vmax[qs]);
        float a = exp2f((mrow[qs]-mnew)*cs);
        mrow[qs] = mnew; lrow[qs] *= a;
        #pragma unroll
        for (int dt=0;dt<8;dt++)
          #pragma unroll
          for (int r=0;r<4;r++) o[qs][dt][r] *= a;
      }
    }
    union PU { unsigned u[4]; bf16x8 v; } P32[2][4];
    #pragma unroll
    for (int qs=0; qs<2; qs++){
      float mc = mrow[qs]*cs;
      float rsum = 0.f;
      #pragma unroll
      for (int kt8=0;kt8<8;kt8++){
        float p0 = exp2f(__builtin_fmaf(s[qs][kt8][0], cs, -mc));
        float p1 = exp2f(__builtin_fmaf(s[qs][kt8][1], cs, -mc));
        float p2 = exp2f(__builtin_fmaf(s[qs][kt8][2], cs, -mc));
        float p3 = exp2f(__builtin_fmaf(s[qs][kt8][3], cs, -mc));
        s[qs][kt8][0]=p0; s[qs][kt8][1]=p1; s[qs][kt8][2]=p2; s[qs][kt8][3]=p3;
        rsum += (p0+p1)+(p2+p3);
      }
      rsum += __shfl_xor(rsum, 16);
      rsum += __shfl_xor(rsum, 32);
      lrow[qs] += rsum;
      #pragma unroll
      for (int kb=0;kb<4;kb++){
        P32[qs][kb].u[0] = pack2bf(s[qs][2*kb][0],   s[qs][2*kb][1]);
        P32[qs][kb].u[1] = pack2bf(s[qs][2*kb][2],   s[qs][2*kb][3]);
        P32[qs][kb].u[2] = pack2bf(s[qs][2*kb+1][0], s[qs][2*kb+1][1]);
        P32[qs][kb].u[3] = pack2bf(s[qs][2*kb+1][2], s[qs][2*kb+1][3]);
      }
    }

    // O^T += V^T P^T : each vf LDS read feeds both q-sets
    __builtin_amdgcn_s_setprio(1);
    #pragma unroll
    for (int kb=0; kb<4; kb++){
      int ca = 4*kb + (q>>1);
      int cb = ca + 2;
      #pragma unroll
      for (int dt=0; dt<8; dt++){
        int d = dt*16 + c16;
        union VU { bf16x4 hh[2]; bf16x8 v; } vf;
        vf.hh[0] = *(const bf16x4*)(Vs + d*128 + ((ca ^ c16) & 15)*8 + (q&1)*4);
        vf.hh[1] = *(const bf16x4*)(Vs + d*128 + ((cb ^ c16) & 15)*8 + (q&1)*4);
        o[0][dt] = __builtin_amdgcn_mfma_f32_16x16x32_bf16(vf.v, P32[0][kb].v, o[0][dt], 0,0,0);
        o[1][dt] = __builtin_amdgcn_mfma_f32_16x16x32_bf16(vf.v, P32[1][kb].v, o[1][dt], 0,0,0);
      }
    }
    __builtin_amdgcn_s_setprio(0);
    __syncthreads();   // drains tile kt+1 glls; certifies buf p readers done
  }

  // normalize + write: lane holds O[q=c16+16qs][d=dt*16+quad*4+r]
  #pragma unroll
  for (int qs=0;qs<2;qs++){
    float inv = 1.f / lrow[qs];
    int qrow = qt*256 + w*32 + qs*16 + c16;
    u16* dst = attnb + ((size_t)(b*SEQ) + qrow)*D_MODEL + h*HD + q*4;
    #pragma unroll
    for (int dt=0;dt<8;dt++){
      ushort4 pk;
      pk.x = f2bf(o[qs][dt][0]*inv);
      pk.y = f2bf(o[qs][dt][1]*inv);
      pk.z = f2bf(o[qs][dt][2]*inv);
      pk.w = f2bf(o[qs][dt][3]*inv);
      *(ushort4*)(dst + dt*16) = pk;
    }
  }
}

extern "C" void kernel_launch(void* const* d_in, const int* in_sizes, int n_in,
                              void* d_out, int out_size, void* d_ws, size_t ws_size,
                              hipStream_t stream) {
  (void)in_sizes; (void)n_in; (void)out_size; (void)ws_size;
  const float* query = (const float*)d_in[0];
  const float* key   = (const float*)d_in[1];
  const float* value = (const float*)d_in[2];
  const float* Wq    = (const float*)d_in[3];
  const float* bq    = (const float*)d_in[4];
  const float* Wk    = (const float*)d_in[5];
  const float* bk    = (const float*)d_in[6];
  const float* Wv    = (const float*)d_in[7];
  const float* bv    = (const float*)d_in[8];
  const float* Wo    = (const float*)d_in[9];
  const float* bo    = (const float*)d_in[10];
  float* out = (float*)d_out;

  char* W = (char*)d_ws;
  u16*  qb     = (u16*) (W + 0);          // 16 MB  bf16 query [4096][2048]
  u16*  kb     = (u16*) (W + 16777216);   // 16 MB  bf16 key
  u16*  vb     = (u16*) (W + 33554432);   // 16 MB  bf16 value
  u16*  WqT    = (u16*) (W + 50331648);   //  8 MB  Wq^T  [2048][2048]
  u16*  WoT    = (u16*) (W + 58720256);   //  8 MB  Wo^T
  u16*  WkT    = (u16*) (W + 67108864);   // .5 MB  Wk^T  [128][2048]
  u16*  WvT    = (u16*) (W + 67633152);   // .5 MB  Wv^T
  u16*  Kp     = (u16*) (W + 84934656);   //  1 MB  K proj bf16 [4096][128]
  u16*  VpT    = (u16*) (W + 85983232);   //  1 MB  V proj^T bf16 [B][128][2048]
  u16*  attnb  = (u16*) (W + 87031808);   // 16 MB  attention out bf16 [4096][2048]
  float* kvpart= (float*)(W + 103809024); // 16 MB  split-K partials [4][2][4096][128]

  prep_kernel<<<16896, 256, 0, stream>>>(
      (const float4*)query, (const float4*)key, (const float4*)value,
      (ushort4*)qb, (ushort4*)kb, (ushort4*)vb,
      Wq, Wo, Wk, Wv, WqT, WoT, WkT, WvT);
  proj_kernel<<<256, 256, 0, stream>>>(kb, vb, WkT, WvT, kvpart);
  kv_reduce_kernel<<<2048, 256, 0, stream>>>(kvpart, bk, bv, Kp, VpT);
  attn_kernel<<<dim3(8,32), 512, 0, stream>>>(qb, WqT, bq, Kp, VpT, attnb);
  oproj_kernel<<<512, 256, 0, stream>>>(attnb, WoT, bo, out);
}